// Round 1
// baseline (732.742 us; speedup 1.0000x reference)
//
#include <hip/hip_runtime.h>
#include <cstdint>
#include <cstddef>

typedef __bf16 bf16;
typedef __bf16 bf16x4 __attribute__((ext_vector_type(4)));
typedef __bf16 bf16x8 __attribute__((ext_vector_type(8)));
typedef float  f32x4 __attribute__((ext_vector_type(4)));

#define DEVI __device__ __forceinline__

// ---------------------------------------------------------------------------
// async global->LDS (16B per lane), CK-style address-space casts
// ---------------------------------------------------------------------------
DEVI void async_ld16(void* lds, const void* g) {
  const __attribute__((address_space(1))) uint32_t* g1 =
      reinterpret_cast<const __attribute__((address_space(1))) uint32_t*>(
          reinterpret_cast<uintptr_t>(g));
  uint32_t lo = (uint32_t)reinterpret_cast<uintptr_t>(lds);
  __attribute__((address_space(3))) uint32_t* l3 =
      reinterpret_cast<__attribute__((address_space(3))) uint32_t*>(lo);
  __builtin_amdgcn_global_load_lds(g1, l3, 16, 0, 0);
}

enum { EPI_BF16 = 0, EPI_SCORES = 2, EPI_DYT = 3, EPI_GELU = 4, EPI_PRIOR = 5 };

// ---------------------------------------------------------------------------
// B^T GEMM: C[row,col] = sum_k A[row,k]*B[col,k]  (both K-contiguous)
// 128x128 tile, BK=64, 4 waves (each 64x64 = 4x4 frags of 16x16x32 MFMA)
// m97 structure: global_load_lds(16B) staging, 2-barrier K-loop.
// ---------------------------------------------------------------------------
template <int EPI>
__global__ __launch_bounds__(256, 2) void gemm_bt(
    const bf16* __restrict__ A, const bf16* __restrict__ Bm, void* __restrict__ Cv,
    int N, int K,
    long long bsA, long long bsB, long long bsC,
    const float* __restrict__ bias, const float* __restrict__ al,
    const float* __restrict__ wv, const float* __restrict__ bv,
    const float* __restrict__ prior, float scale)
{
  __shared__ __align__(16) bf16 As[128 * 64];
  __shared__ __align__(16) bf16 Bs[128 * 64];
  const int tid = threadIdx.x;
  const int bx = blockIdx.x, by = blockIdx.y, bz = blockIdx.z;
  const bf16* Ab = A  + (size_t)bz * bsA + (size_t)by * 128 * K;
  const bf16* Bb = Bm + (size_t)bz * bsB + (size_t)bx * 128 * K;

  const int lane = tid & 63;
  const int wid  = tid >> 6;
  const int wr = (wid >> 1) * 64;
  const int wc = (wid & 1) * 64;
  const int l15 = lane & 15;
  const int lhi = lane >> 4;

  f32x4 acc[4][4];
  const f32x4 zero = {0.f, 0.f, 0.f, 0.f};
#pragma unroll
  for (int i = 0; i < 4; ++i)
#pragma unroll
    for (int j = 0; j < 4; ++j) acc[i][j] = zero;

  const int srow = tid >> 3;        // 32 rows per 256-chunk
  const int skk  = (tid & 7) << 3;  // 8 k-elems per 16B

  for (int kt = 0; kt < K; kt += 64) {
#pragma unroll
    for (int it = 0; it < 4; ++it) {
      const int row = srow + it * 32;
      async_ld16(&As[row * 64 + skk], Ab + (size_t)row * K + kt + skk);
    }
#pragma unroll
    for (int it = 0; it < 4; ++it) {
      const int row = srow + it * 32;
      async_ld16(&Bs[row * 64 + skk], Bb + (size_t)row * K + kt + skk);
    }
    asm volatile("s_waitcnt vmcnt(0)" ::: "memory");
    __syncthreads();
#pragma unroll
    for (int ks = 0; ks < 2; ++ks) {
      const int kb = ks * 32 + lhi * 8;
      bf16x8 af[4], bfv[4];
#pragma unroll
      for (int m = 0; m < 4; ++m)
        af[m] = *(const bf16x8*)&As[(wr + m * 16 + l15) * 64 + kb];
#pragma unroll
      for (int n = 0; n < 4; ++n)
        bfv[n] = *(const bf16x8*)&Bs[(wc + n * 16 + l15) * 64 + kb];
#pragma unroll
      for (int m = 0; m < 4; ++m)
#pragma unroll
        for (int n = 0; n < 4; ++n)
          acc[m][n] = __builtin_amdgcn_mfma_f32_16x16x32_bf16(af[m], bfv[n], acc[m][n], 0, 0, 0);
    }
    __syncthreads();
  }

  // epilogue: C/D layout col = lane&15, row = (lane>>4)*4 + reg
  const int crow0 = by * 128 + wr + (lhi << 2);
  const int ccol0 = bx * 128 + wc + l15;

  float a2 = 0.f;
  if constexpr (EPI == EPI_DYT) a2 = al[0];

#pragma unroll
  for (int n = 0; n < 4; ++n) {
    const int col = ccol0 + n * 16;
    float bcol = 0.f, wcol = 0.f, bvcol = 0.f;
    if constexpr (EPI == EPI_DYT || EPI == EPI_GELU || EPI == EPI_PRIOR) bcol = bias[col];
    if constexpr (EPI == EPI_DYT) { wcol = wv[col]; bvcol = bv[col]; }
#pragma unroll
    for (int m = 0; m < 4; ++m) {
#pragma unroll
      for (int r = 0; r < 4; ++r) {
        const int row = crow0 + m * 16 + r;
        const float v = acc[m][n][r];
        if constexpr (EPI == EPI_BF16) {
          bf16* C = (bf16*)Cv + (size_t)bz * bsC;
          C[(size_t)row * N + col] = (bf16)v;
        } else if constexpr (EPI == EPI_SCORES) {
          float* C = (float*)Cv + (size_t)bz * bsC;
          C[(size_t)row * N + col] = v * scale - fabsf((float)(row - col));
        } else if constexpr (EPI == EPI_DYT) {
          bf16* C = (bf16*)Cv + (size_t)bz * bsC;
          C[(size_t)row * N + col] = (bf16)(tanhf(a2 * (v + bcol)) * wcol + bvcol);
        } else if constexpr (EPI == EPI_GELU) {
          bf16* C = (bf16*)Cv + (size_t)bz * bsC;
          const float g = v + bcol;
          C[(size_t)row * N + col] = (bf16)(0.5f * g * (1.0f + erff(g * 0.70710678118654752f)));
        } else {  // EPI_PRIOR: fp32 posterior = h + b + prior
          float* C = (float*)Cv;
          C[(size_t)row * N + col] = v + bcol + prior[(size_t)row * N + col];
        }
      }
    }
  }
}

// ---------------------------------------------------------------------------
// fused: xpe = x + pos_embed; prior = dyt3(xpe) (fp32); xn = dyt1(xpe) (bf16)
// ---------------------------------------------------------------------------
__global__ __launch_bounds__(256) void ew_pre(
    const float* __restrict__ x, const float* __restrict__ pe,
    const float* __restrict__ a1p, const float* __restrict__ w1, const float* __restrict__ b1,
    const float* __restrict__ a3p, const float* __restrict__ w3, const float* __restrict__ b3,
    float* __restrict__ prior, bf16* __restrict__ xn, int total4)
{
  const float a1 = a1p[0], a3 = a3p[0];
  for (int i = blockIdx.x * 256 + threadIdx.x; i < total4; i += gridDim.x * 256) {
    const int dq = i & 255;  // D/4 = 256
    const float4 xv  = ((const float4*)x)[i];
    const float4 pv  = ((const float4*)pe)[dq];
    const float4 w1v = ((const float4*)w1)[dq];
    const float4 b1v = ((const float4*)b1)[dq];
    const float4 w3v = ((const float4*)w3)[dq];
    const float4 b3v = ((const float4*)b3)[dq];
    const float x0 = xv.x + pv.x, x1 = xv.y + pv.y, x2 = xv.z + pv.z, x3 = xv.w + pv.w;
    float4 prv;
    prv.x = tanhf(a3 * x0) * w3v.x + b3v.x;
    prv.y = tanhf(a3 * x1) * w3v.y + b3v.y;
    prv.z = tanhf(a3 * x2) * w3v.z + b3v.z;
    prv.w = tanhf(a3 * x3) * w3v.w + b3v.w;
    ((float4*)prior)[i] = prv;
    bf16x4 o;
    o[0] = (bf16)(tanhf(a1 * x0) * w1v.x + b1v.x);
    o[1] = (bf16)(tanhf(a1 * x1) * w1v.y + b1v.y);
    o[2] = (bf16)(tanhf(a1 * x2) * w1v.z + b1v.z);
    o[3] = (bf16)(tanhf(a1 * x3) * w1v.w + b1v.w);
    ((bf16x4*)xn)[i] = o;
  }
}

// fp32 -> bf16 weight conversion, 6 segments via blockIdx.y
__global__ __launch_bounds__(256) void conv_w(
    const float* __restrict__ s0, const float* __restrict__ s1, const float* __restrict__ s2,
    const float* __restrict__ s3, const float* __restrict__ s4, const float* __restrict__ s5,
    bf16* __restrict__ d0, bf16* __restrict__ d1, bf16* __restrict__ d2,
    bf16* __restrict__ d3, bf16* __restrict__ d4, bf16* __restrict__ d5,
    int n0, int n1, int n2, int n3, int n4, int n5)
{
  const float* s; bf16* d; int n;
  switch (blockIdx.y) {
    case 0: s = s0; d = d0; n = n0; break;
    case 1: s = s1; d = d1; n = n1; break;
    case 2: s = s2; d = d2; n = n2; break;
    case 3: s = s3; d = d3; n = n3; break;
    case 4: s = s4; d = d4; n = n4; break;
    default: s = s5; d = d5; n = n5; break;
  }
  const int nq = n >> 2;
  for (int i = blockIdx.x * 256 + threadIdx.x; i < nq; i += gridDim.x * 256) {
    const float4 v = ((const float4*)s)[i];
    bf16x4 o;
    o[0] = (bf16)v.x; o[1] = (bf16)v.y; o[2] = (bf16)v.z; o[3] = (bf16)v.w;
    ((bf16x4*)d)[i] = o;
  }
}

// V [B][T][D] -> Vt [B][D][T], 64x64 LDS tiles
__global__ __launch_bounds__(256) void transpose_k(const bf16* __restrict__ in, bf16* __restrict__ out) {
  __shared__ bf16 tile[64][65];
  const int bx = blockIdx.x;  // D/64
  const int by = blockIdx.y;  // T/64
  const int bz = blockIdx.z;
  const bf16* ib = in  + (size_t)bz * 2048 * 1024;
  bf16* ob       = out + (size_t)bz * 1024 * 2048;
  const int tx = threadIdx.x & 15, ty = threadIdx.x >> 4;
#pragma unroll
  for (int i = 0; i < 4; ++i) {
    const int r = ty + i * 16;
    const bf16x4 v = *(const bf16x4*)(ib + (size_t)(by * 64 + r) * 1024 + bx * 64 + tx * 4);
    tile[r][tx * 4 + 0] = v[0]; tile[r][tx * 4 + 1] = v[1];
    tile[r][tx * 4 + 2] = v[2]; tile[r][tx * 4 + 3] = v[3];
  }
  __syncthreads();
#pragma unroll
  for (int i = 0; i < 4; ++i) {
    const int r = ty + i * 16;   // d_local
    const int c = tx * 4;        // t_local
    bf16x4 v;
    v[0] = tile[c + 0][r]; v[1] = tile[c + 1][r];
    v[2] = tile[c + 2][r]; v[3] = tile[c + 3][r];
    *(bf16x4*)(ob + (size_t)(bx * 64 + r) * 2048 + by * 64 + c) = v;
  }
}

// ---------------------------------------------------------------------------
// reductions
// ---------------------------------------------------------------------------
DEVI float wave_red_max(float v) {
#pragma unroll
  for (int o = 32; o > 0; o >>= 1) v = fmaxf(v, __shfl_xor(v, o));
  return v;
}
DEVI float wave_red_sum(float v) {
#pragma unroll
  for (int o = 32; o > 0; o >>= 1) v += __shfl_xor(v, o);
  return v;
}
DEVI float block_red_max(float v, float* sm) {
  v = wave_red_max(v);
  if ((threadIdx.x & 63) == 0) sm[threadIdx.x >> 6] = v;
  __syncthreads();
  v = fmaxf(fmaxf(sm[0], sm[1]), fmaxf(sm[2], sm[3]));
  __syncthreads();
  return v;
}
DEVI float block_red_sum(float v, float* sm) {
  v = wave_red_sum(v);
  if ((threadIdx.x & 63) == 0) sm[threadIdx.x >> 6] = v;
  __syncthreads();
  v = sm[0] + sm[1] + sm[2] + sm[3];
  __syncthreads();
  return v;
}

// row softmax over 2048 scores (fp32 in) -> bf16 probs
__global__ __launch_bounds__(256) void softmax_k(const float* __restrict__ scores, bf16* __restrict__ probs) {
  __shared__ float sm[4];
  const size_t row = blockIdx.x;
  const float* s = scores + row * 2048;
  bf16* p = probs + row * 2048;
  const int t = threadIdx.x;
  const float4 v0 = *(const float4*)&s[t * 4];
  const float4 v1 = *(const float4*)&s[1024 + t * 4];
  float mx = fmaxf(fmaxf(fmaxf(v0.x, v0.y), fmaxf(v0.z, v0.w)),
                   fmaxf(fmaxf(v1.x, v1.y), fmaxf(v1.z, v1.w)));
  mx = block_red_max(mx, sm);
  const float e0 = expf(v0.x - mx), e1 = expf(v0.y - mx), e2 = expf(v0.z - mx), e3 = expf(v0.w - mx);
  const float e4 = expf(v1.x - mx), e5 = expf(v1.y - mx), e6 = expf(v1.z - mx), e7 = expf(v1.w - mx);
  float ssum = e0 + e1 + e2 + e3 + e4 + e5 + e6 + e7;
  ssum = block_red_sum(ssum, sm);
  const float inv = 1.0f / ssum;
  bf16x4 o0, o1;
  o0[0] = (bf16)(e0 * inv); o0[1] = (bf16)(e1 * inv); o0[2] = (bf16)(e2 * inv); o0[3] = (bf16)(e3 * inv);
  o1[0] = (bf16)(e4 * inv); o1[1] = (bf16)(e5 * inv); o1[2] = (bf16)(e6 * inv); o1[3] = (bf16)(e7 * inv);
  *(bf16x4*)&p[t * 4] = o0;
  *(bf16x4*)&p[1024 + t * 4] = o1;
}

// per-row JS pieces: kl1_row = sum p_m*(m - pr) + (logZp - logZm); same for post
__global__ __launch_bounds__(256) void loss_k(const float* __restrict__ prior,
                                              const float* __restrict__ post,
                                              float* __restrict__ acc) {
  __shared__ float sm[4];
  const size_t row = blockIdx.x;
  const int t = threadIdx.x;
  const float4 pr = *(const float4*)&prior[row * 1024 + t * 4];
  const float4 po = *(const float4*)&post[row * 1024 + t * 4];
  float4 mm;
  mm.x = 0.5f * (pr.x + po.x); mm.y = 0.5f * (pr.y + po.y);
  mm.z = 0.5f * (pr.z + po.z); mm.w = 0.5f * (pr.w + po.w);
  const float mxp = block_red_max(fmaxf(fmaxf(pr.x, pr.y), fmaxf(pr.z, pr.w)), sm);
  const float mxo = block_red_max(fmaxf(fmaxf(po.x, po.y), fmaxf(po.z, po.w)), sm);
  const float mxm = block_red_max(fmaxf(fmaxf(mm.x, mm.y), fmaxf(mm.z, mm.w)), sm);
  float sp = expf(pr.x - mxp) + expf(pr.y - mxp) + expf(pr.z - mxp) + expf(pr.w - mxp);
  sp = block_red_sum(sp, sm);
  float so = expf(po.x - mxo) + expf(po.y - mxo) + expf(po.z - mxo) + expf(po.w - mxo);
  so = block_red_sum(so, sm);
  const float em0 = expf(mm.x - mxm), em1 = expf(mm.y - mxm), em2 = expf(mm.z - mxm), em3 = expf(mm.w - mxm);
  float smm = block_red_sum(em0 + em1 + em2 + em3, sm);
  const float invm = 1.0f / smm;
  float s1 = em0 * invm * (mm.x - pr.x) + em1 * invm * (mm.y - pr.y) +
             em2 * invm * (mm.z - pr.z) + em3 * invm * (mm.w - pr.w);
  float s2 = em0 * invm * (mm.x - po.x) + em1 * invm * (mm.y - po.y) +
             em2 * invm * (mm.z - po.z) + em3 * invm * (mm.w - po.w);
  s1 = block_red_sum(s1, sm);
  s2 = block_red_sum(s2, sm);
  if (t == 0) {
    const float logZp = mxp + logf(sp);
    const float logZo = mxo + logf(so);
    const float logZm = mxm + logf(smm);
    atomicAdd(&acc[0], s1 + (logZp - logZm));
    atomicAdd(&acc[1], s2 + (logZo - logZm));
  }
}

__global__ void fin_k(const float* __restrict__ acc, float* __restrict__ out) {
  if (threadIdx.x == 0 && blockIdx.x == 0)
    out[0] = 0.125f * (acc[0] + acc[1]);  // 0.5*(kl1+kl2)/B, B=4
}

// ---------------------------------------------------------------------------
extern "C" void kernel_launch(void* const* d_in, const int* in_sizes, int n_in,
                              void* d_out, int out_size, void* d_ws, size_t ws_size,
                              hipStream_t stream) {
  const float* x  = (const float*)d_in[0];
  const float* pe = (const float*)d_in[1];
  const float* a1 = (const float*)d_in[2];
  const float* w1 = (const float*)d_in[3];
  const float* b1 = (const float*)d_in[4];
  const float* a2 = (const float*)d_in[5];
  const float* w2 = (const float*)d_in[6];
  const float* b2 = (const float*)d_in[7];
  const float* a3 = (const float*)d_in[8];
  const float* w3 = (const float*)d_in[9];
  const float* b3 = (const float*)d_in[10];
  const float* Wq = (const float*)d_in[11];
  const float* Wk = (const float*)d_in[12];
  const float* Wv = (const float*)d_in[13];
  const float* Wp = (const float*)d_in[14];
  const float* bp = (const float*)d_in[15];
  const float* We = (const float*)d_in[16];
  const float* be = (const float*)d_in[17];
  const float* Wc = (const float*)d_in[18];
  const float* bc = (const float*)d_in[19];
  float* out = (float*)d_out;

  char* ws = (char*)d_ws;
  float* prior  = (float*)(ws + 0);              // 33.55 MB fp32
  bf16*  xn     = (bf16*)(ws + 33554432ull);     // 16.78 MB bf16 (reused: attn out)
  bf16*  Qb     = (bf16*)(ws + 50331648ull);     // (reused: h2)
  bf16*  Kb     = (bf16*)(ws + 67108864ull);
  bf16*  Vb     = (bf16*)(ws + 83886080ull);
  bf16*  Vt     = (bf16*)(ws + 100663296ull);
  float* scores = (float*)(ws + 117440512ull);   // 67.1 MB fp32 (reused: e bf16)
  bf16*  Wqb    = (bf16*)(ws + 184549376ull);
  bf16*  Wkb    = (bf16*)(ws + 186646528ull);
  bf16*  Wvb    = (bf16*)(ws + 188743680ull);
  bf16*  Wpb    = (bf16*)(ws + 190840832ull);
  bf16*  Web    = (bf16*)(ws + 192937984ull);
  bf16*  Wcb    = (bf16*)(ws + 201326592ull);
  float* acc    = (float*)(ws + 209715200ull);
  bf16*  attno  = xn;
  bf16*  h2     = Qb;
  bf16*  eb     = (bf16*)scores;
  bf16*  probs  = (bf16*)d_out;  // 33,554,432 B <= out buffer; consumed before posterior write

  dim3 blk(256);

  conv_w<<<dim3(1024, 6), blk, 0, stream>>>(Wq, Wk, Wv, Wp, We, Wc,
                                            Wqb, Wkb, Wvb, Wpb, Web, Wcb,
                                            1048576, 1048576, 1048576, 1048576, 4194304, 4194304);
  ew_pre<<<2048, blk, 0, stream>>>(x, pe, a1, w1, b1, a3, w3, b3, prior, xn, 2097152);

  // QKV: [8192,1024] = xn @ W^T
  gemm_bt<EPI_BF16><<<dim3(8, 64, 1), blk, 0, stream>>>(xn, Wqb, Qb, 1024, 1024, 0, 0, 0,
      nullptr, nullptr, nullptr, nullptr, nullptr, 0.f);
  gemm_bt<EPI_BF16><<<dim3(8, 64, 1), blk, 0, stream>>>(xn, Wkb, Kb, 1024, 1024, 0, 0, 0,
      nullptr, nullptr, nullptr, nullptr, nullptr, 0.f);
  gemm_bt<EPI_BF16><<<dim3(8, 64, 1), blk, 0, stream>>>(xn, Wvb, Vb, 1024, 1024, 0, 0, 0,
      nullptr, nullptr, nullptr, nullptr, nullptr, 0.f);
  transpose_k<<<dim3(16, 32, 4), blk, 0, stream>>>(Vb, Vt);

  // scores[b,t,s] = (Q·K)/32 - |t-s|
  gemm_bt<EPI_SCORES><<<dim3(16, 16, 4), blk, 0, stream>>>(Qb, Kb, scores, 2048, 1024,
      2097152ll, 2097152ll, 4194304ll, nullptr, nullptr, nullptr, nullptr, nullptr, 0.03125f);
  softmax_k<<<8192, blk, 0, stream>>>(scores, probs);

  // out[b,t,d] = probs @ V  (B = Vt[b][d][s], K-contiguous)
  gemm_bt<EPI_BF16><<<dim3(8, 16, 4), blk, 0, stream>>>(probs, Vt, attno, 1024, 2048,
      4194304ll, 2097152ll, 2097152ll, nullptr, nullptr, nullptr, nullptr, nullptr, 0.f);

  // proj + dyt2
  gemm_bt<EPI_DYT><<<dim3(8, 64, 1), blk, 0, stream>>>(attno, Wpb, h2, 1024, 1024, 0, 0, 0,
      bp, a2, w2, b2, nullptr, 0.f);
  // expand + exact gelu
  gemm_bt<EPI_GELU><<<dim3(32, 64, 1), blk, 0, stream>>>(h2, Web, eb, 4096, 1024, 0, 0, 0,
      be, nullptr, nullptr, nullptr, nullptr, 0.f);
  // contract + bias + prior -> posterior (fp32, d_out)
  gemm_bt<EPI_PRIOR><<<dim3(8, 64, 1), blk, 0, stream>>>(eb, Wcb, out, 1024, 4096, 0, 0, 0,
      bc, nullptr, nullptr, nullptr, prior, 0.f);

  hipMemsetAsync(acc, 0, 2 * sizeof(float), stream);
  loss_k<<<8192, blk, 0, stream>>>(prior, out, acc);
  fin_k<<<1, 1, 0, stream>>>(acc, out + 8388608);
}

// Round 2
// 533.240 us; speedup vs baseline: 1.3741x; 1.3741x over previous
//
#include <hip/hip_runtime.h>
#include <cstdint>
#include <cstddef>

typedef __bf16 bf16;
typedef __bf16 bf16x4 __attribute__((ext_vector_type(4)));
typedef __bf16 bf16x8 __attribute__((ext_vector_type(8)));
typedef float  f32x4 __attribute__((ext_vector_type(4)));

#define DEVI __device__ __forceinline__

// ---------------------------------------------------------------------------
// async global->LDS (16B per lane), CK-style address-space casts
// ---------------------------------------------------------------------------
DEVI void async_ld16(void* lds, const void* g) {
  const __attribute__((address_space(1))) uint32_t* g1 =
      reinterpret_cast<const __attribute__((address_space(1))) uint32_t*>(
          reinterpret_cast<uintptr_t>(g));
  uint32_t lo = (uint32_t)reinterpret_cast<uintptr_t>(lds);
  __attribute__((address_space(3))) uint32_t* l3 =
      reinterpret_cast<__attribute__((address_space(3))) uint32_t*>(lo);
  __builtin_amdgcn_global_load_lds(g1, l3, 16, 0, 0);
}

enum { EPI_BF16 = 0, EPI_SCORES = 2, EPI_DYT = 3, EPI_GELU = 4, EPI_PRIOR = 5 };

// ---------------------------------------------------------------------------
// B^T GEMM: C[row,col] = sum_k A[row,k]*B[col,k]  (both K-contiguous)
// 128x128 tile, BK=64, 4 waves (each 64x64 = 4x4 frags of 16x16x32 MFMA)
// m97 structure: global_load_lds(16B) staging, 2-barrier K-loop.
// ---------------------------------------------------------------------------
template <int EPI>
__global__ __launch_bounds__(256, 2) void gemm_bt(
    const bf16* __restrict__ A, const bf16* __restrict__ Bm, void* __restrict__ Cv,
    int N, int K,
    long long bsA, long long bsB, long long bsC,
    const float* __restrict__ bias, const float* __restrict__ al,
    const float* __restrict__ wv, const float* __restrict__ bv,
    const float* __restrict__ prior, float scale)
{
  __shared__ __align__(16) bf16 As[128 * 64];
  __shared__ __align__(16) bf16 Bs[128 * 64];
  const int tid = threadIdx.x;
  const int bx = blockIdx.x, by = blockIdx.y, bz = blockIdx.z;
  const bf16* Ab = A  + (size_t)bz * bsA + (size_t)by * 128 * K;
  const bf16* Bb = Bm + (size_t)bz * bsB + (size_t)bx * 128 * K;

  const int lane = tid & 63;
  const int wid  = tid >> 6;
  const int wr = (wid >> 1) * 64;
  const int wc = (wid & 1) * 64;
  const int l15 = lane & 15;
  const int lhi = lane >> 4;

  f32x4 acc[4][4];
  const f32x4 zero = {0.f, 0.f, 0.f, 0.f};
#pragma unroll
  for (int i = 0; i < 4; ++i)
#pragma unroll
    for (int j = 0; j < 4; ++j) acc[i][j] = zero;

  const int srow = tid >> 3;        // 32 rows per 256-chunk
  const int skk  = (tid & 7) << 3;  // 8 k-elems per 16B

  for (int kt = 0; kt < K; kt += 64) {
#pragma unroll
    for (int it = 0; it < 4; ++it) {
      const int row = srow + it * 32;
      async_ld16(&As[row * 64 + skk], Ab + (size_t)row * K + kt + skk);
    }
#pragma unroll
    for (int it = 0; it < 4; ++it) {
      const int row = srow + it * 32;
      async_ld16(&Bs[row * 64 + skk], Bb + (size_t)row * K + kt + skk);
    }
    asm volatile("s_waitcnt vmcnt(0)" ::: "memory");
    __syncthreads();
#pragma unroll
    for (int ks = 0; ks < 2; ++ks) {
      const int kb = ks * 32 + lhi * 8;
      bf16x8 af[4], bfv[4];
#pragma unroll
      for (int m = 0; m < 4; ++m)
        af[m] = *(const bf16x8*)&As[(wr + m * 16 + l15) * 64 + kb];
#pragma unroll
      for (int n = 0; n < 4; ++n)
        bfv[n] = *(const bf16x8*)&Bs[(wc + n * 16 + l15) * 64 + kb];
#pragma unroll
      for (int m = 0; m < 4; ++m)
#pragma unroll
        for (int n = 0; n < 4; ++n)
          acc[m][n] = __builtin_amdgcn_mfma_f32_16x16x32_bf16(af[m], bfv[n], acc[m][n], 0, 0, 0);
    }
    __syncthreads();
  }

  // epilogue: C/D layout col = lane&15, row = (lane>>4)*4 + reg
  const int crow0 = by * 128 + wr + (lhi << 2);
  const int ccol0 = bx * 128 + wc + l15;

  float a2 = 0.f;
  if constexpr (EPI == EPI_DYT) a2 = al[0];

#pragma unroll
  for (int n = 0; n < 4; ++n) {
    const int col = ccol0 + n * 16;
    float bcol = 0.f, wcol = 0.f, bvcol = 0.f;
    if constexpr (EPI == EPI_DYT || EPI == EPI_GELU || EPI == EPI_PRIOR) bcol = bias[col];
    if constexpr (EPI == EPI_DYT) { wcol = wv[col]; bvcol = bv[col]; }
#pragma unroll
    for (int m = 0; m < 4; ++m) {
#pragma unroll
      for (int r = 0; r < 4; ++r) {
        const int row = crow0 + m * 16 + r;
        const float v = acc[m][n][r];
        if constexpr (EPI == EPI_BF16) {
          bf16* C = (bf16*)Cv + (size_t)bz * bsC;
          C[(size_t)row * N + col] = (bf16)v;
        } else if constexpr (EPI == EPI_SCORES) {
          float* C = (float*)Cv + (size_t)bz * bsC;
          C[(size_t)row * N + col] = v * scale - fabsf((float)(row - col));
        } else if constexpr (EPI == EPI_DYT) {
          bf16* C = (bf16*)Cv + (size_t)bz * bsC;
          C[(size_t)row * N + col] = (bf16)(tanhf(a2 * (v + bcol)) * wcol + bvcol);
        } else if constexpr (EPI == EPI_GELU) {
          bf16* C = (bf16*)Cv + (size_t)bz * bsC;
          const float g = v + bcol;
          C[(size_t)row * N + col] = (bf16)(0.5f * g * (1.0f + erff(g * 0.70710678118654752f)));
        } else {  // EPI_PRIOR: fp32 posterior = h + b + prior
          float* C = (float*)Cv;
          C[(size_t)row * N + col] = v + bcol + prior[(size_t)row * N + col];
        }
      }
    }
  }
}

// ---------------------------------------------------------------------------
// fused: xpe = x + pos_embed; prior = dyt3(xpe) (fp32); xn = dyt1(xpe) (bf16)
// ---------------------------------------------------------------------------
__global__ __launch_bounds__(256) void ew_pre(
    const float* __restrict__ x, const float* __restrict__ pe,
    const float* __restrict__ a1p, const float* __restrict__ w1, const float* __restrict__ b1,
    const float* __restrict__ a3p, const float* __restrict__ w3, const float* __restrict__ b3,
    float* __restrict__ prior, bf16* __restrict__ xn, int total4)
{
  const float a1 = a1p[0], a3 = a3p[0];
  for (int i = blockIdx.x * 256 + threadIdx.x; i < total4; i += gridDim.x * 256) {
    const int dq = i & 255;  // D/4 = 256
    const float4 xv  = ((const float4*)x)[i];
    const float4 pv  = ((const float4*)pe)[dq];
    const float4 w1v = ((const float4*)w1)[dq];
    const float4 b1v = ((const float4*)b1)[dq];
    const float4 w3v = ((const float4*)w3)[dq];
    const float4 b3v = ((const float4*)b3)[dq];
    const float x0 = xv.x + pv.x, x1 = xv.y + pv.y, x2 = xv.z + pv.z, x3 = xv.w + pv.w;
    float4 prv;
    prv.x = tanhf(a3 * x0) * w3v.x + b3v.x;
    prv.y = tanhf(a3 * x1) * w3v.y + b3v.y;
    prv.z = tanhf(a3 * x2) * w3v.z + b3v.z;
    prv.w = tanhf(a3 * x3) * w3v.w + b3v.w;
    ((float4*)prior)[i] = prv;
    bf16x4 o;
    o[0] = (bf16)(tanhf(a1 * x0) * w1v.x + b1v.x);
    o[1] = (bf16)(tanhf(a1 * x1) * w1v.y + b1v.y);
    o[2] = (bf16)(tanhf(a1 * x2) * w1v.z + b1v.z);
    o[3] = (bf16)(tanhf(a1 * x3) * w1v.w + b1v.w);
    ((bf16x4*)xn)[i] = o;
  }
}

// fp32 -> bf16 weight conversion, 6 segments via blockIdx.y
__global__ __launch_bounds__(256) void conv_w(
    const float* __restrict__ s0, const float* __restrict__ s1, const float* __restrict__ s2,
    const float* __restrict__ s3, const float* __restrict__ s4, const float* __restrict__ s5,
    bf16* __restrict__ d0, bf16* __restrict__ d1, bf16* __restrict__ d2,
    bf16* __restrict__ d3, bf16* __restrict__ d4, bf16* __restrict__ d5,
    int n0, int n1, int n2, int n3, int n4, int n5)
{
  const float* s; bf16* d; int n;
  switch (blockIdx.y) {
    case 0: s = s0; d = d0; n = n0; break;
    case 1: s = s1; d = d1; n = n1; break;
    case 2: s = s2; d = d2; n = n2; break;
    case 3: s = s3; d = d3; n = n3; break;
    case 4: s = s4; d = d4; n = n4; break;
    default: s = s5; d = d5; n = n5; break;
  }
  const int nq = n >> 2;
  for (int i = blockIdx.x * 256 + threadIdx.x; i < nq; i += gridDim.x * 256) {
    const float4 v = ((const float4*)s)[i];
    bf16x4 o;
    o[0] = (bf16)v.x; o[1] = (bf16)v.y; o[2] = (bf16)v.z; o[3] = (bf16)v.w;
    ((bf16x4*)d)[i] = o;
  }
}

// V [B][T][D] -> Vt [B][D][T], 64x64 LDS tiles
__global__ __launch_bounds__(256) void transpose_k(const bf16* __restrict__ in, bf16* __restrict__ out) {
  __shared__ bf16 tile[64][65];
  const int bx = blockIdx.x;  // D/64
  const int by = blockIdx.y;  // T/64
  const int bz = blockIdx.z;
  const bf16* ib = in  + (size_t)bz * 2048 * 1024;
  bf16* ob       = out + (size_t)bz * 1024 * 2048;
  const int tx = threadIdx.x & 15, ty = threadIdx.x >> 4;
#pragma unroll
  for (int i = 0; i < 4; ++i) {
    const int r = ty + i * 16;
    const bf16x4 v = *(const bf16x4*)(ib + (size_t)(by * 64 + r) * 1024 + bx * 64 + tx * 4);
    tile[r][tx * 4 + 0] = v[0]; tile[r][tx * 4 + 1] = v[1];
    tile[r][tx * 4 + 2] = v[2]; tile[r][tx * 4 + 3] = v[3];
  }
  __syncthreads();
#pragma unroll
  for (int i = 0; i < 4; ++i) {
    const int r = ty + i * 16;   // d_local
    const int c = tx * 4;        // t_local
    bf16x4 v;
    v[0] = tile[c + 0][r]; v[1] = tile[c + 1][r];
    v[2] = tile[c + 2][r]; v[3] = tile[c + 3][r];
    *(bf16x4*)(ob + (size_t)(bx * 64 + r) * 2048 + by * 64 + c) = v;
  }
}

// ---------------------------------------------------------------------------
// reductions
// ---------------------------------------------------------------------------
DEVI float wave_red_max(float v) {
#pragma unroll
  for (int o = 32; o > 0; o >>= 1) v = fmaxf(v, __shfl_xor(v, o));
  return v;
}
DEVI float wave_red_sum(float v) {
#pragma unroll
  for (int o = 32; o > 0; o >>= 1) v += __shfl_xor(v, o);
  return v;
}
DEVI float block_red_max(float v, float* sm) {
  v = wave_red_max(v);
  if ((threadIdx.x & 63) == 0) sm[threadIdx.x >> 6] = v;
  __syncthreads();
  v = fmaxf(fmaxf(sm[0], sm[1]), fmaxf(sm[2], sm[3]));
  __syncthreads();
  return v;
}
DEVI float block_red_sum(float v, float* sm) {
  v = wave_red_sum(v);
  if ((threadIdx.x & 63) == 0) sm[threadIdx.x >> 6] = v;
  __syncthreads();
  v = sm[0] + sm[1] + sm[2] + sm[3];
  __syncthreads();
  return v;
}

// row softmax over 2048 scores (fp32 in) -> bf16 probs
__global__ __launch_bounds__(256) void softmax_k(const float* __restrict__ scores, bf16* __restrict__ probs) {
  __shared__ float sm[4];
  const size_t row = blockIdx.x;
  const float* s = scores + row * 2048;
  bf16* p = probs + row * 2048;
  const int t = threadIdx.x;
  const float4 v0 = *(const float4*)&s[t * 4];
  const float4 v1 = *(const float4*)&s[1024 + t * 4];
  float mx = fmaxf(fmaxf(fmaxf(v0.x, v0.y), fmaxf(v0.z, v0.w)),
                   fmaxf(fmaxf(v1.x, v1.y), fmaxf(v1.z, v1.w)));
  mx = block_red_max(mx, sm);
  const float e0 = expf(v0.x - mx), e1 = expf(v0.y - mx), e2 = expf(v0.z - mx), e3 = expf(v0.w - mx);
  const float e4 = expf(v1.x - mx), e5 = expf(v1.y - mx), e6 = expf(v1.z - mx), e7 = expf(v1.w - mx);
  float ssum = e0 + e1 + e2 + e3 + e4 + e5 + e6 + e7;
  ssum = block_red_sum(ssum, sm);
  const float inv = 1.0f / ssum;
  bf16x4 o0, o1;
  o0[0] = (bf16)(e0 * inv); o0[1] = (bf16)(e1 * inv); o0[2] = (bf16)(e2 * inv); o0[3] = (bf16)(e3 * inv);
  o1[0] = (bf16)(e4 * inv); o1[1] = (bf16)(e5 * inv); o1[2] = (bf16)(e6 * inv); o1[3] = (bf16)(e7 * inv);
  *(bf16x4*)&p[t * 4] = o0;
  *(bf16x4*)&p[1024 + t * 4] = o1;
}

// per-row JS pieces -> per-row partials (NO global atomics; 2-stage reduce)
__global__ __launch_bounds__(256) void loss_k(const float* __restrict__ prior,
                                              const float* __restrict__ post,
                                              float* __restrict__ partial) {
  __shared__ float sm[4];
  const size_t row = blockIdx.x;
  const int t = threadIdx.x;
  const float4 pr = *(const float4*)&prior[row * 1024 + t * 4];
  const float4 po = *(const float4*)&post[row * 1024 + t * 4];
  float4 mm;
  mm.x = 0.5f * (pr.x + po.x); mm.y = 0.5f * (pr.y + po.y);
  mm.z = 0.5f * (pr.z + po.z); mm.w = 0.5f * (pr.w + po.w);
  const float mxp = block_red_max(fmaxf(fmaxf(pr.x, pr.y), fmaxf(pr.z, pr.w)), sm);
  const float mxo = block_red_max(fmaxf(fmaxf(po.x, po.y), fmaxf(po.z, po.w)), sm);
  const float mxm = block_red_max(fmaxf(fmaxf(mm.x, mm.y), fmaxf(mm.z, mm.w)), sm);
  float sp = expf(pr.x - mxp) + expf(pr.y - mxp) + expf(pr.z - mxp) + expf(pr.w - mxp);
  sp = block_red_sum(sp, sm);
  float so = expf(po.x - mxo) + expf(po.y - mxo) + expf(po.z - mxo) + expf(po.w - mxo);
  so = block_red_sum(so, sm);
  const float em0 = expf(mm.x - mxm), em1 = expf(mm.y - mxm), em2 = expf(mm.z - mxm), em3 = expf(mm.w - mxm);
  float smm = block_red_sum(em0 + em1 + em2 + em3, sm);
  const float invm = 1.0f / smm;
  float s1 = em0 * invm * (mm.x - pr.x) + em1 * invm * (mm.y - pr.y) +
             em2 * invm * (mm.z - pr.z) + em3 * invm * (mm.w - pr.w);
  float s2 = em0 * invm * (mm.x - po.x) + em1 * invm * (mm.y - po.y) +
             em2 * invm * (mm.z - po.z) + em3 * invm * (mm.w - po.w);
  s1 = block_red_sum(s1, sm);
  s2 = block_red_sum(s2, sm);
  if (t == 0) {
    const float logZp = mxp + logf(sp);
    const float logZo = mxo + logf(so);
    const float logZm = mxm + logf(smm);
    partial[row]        = s1 + (logZp - logZm);
    partial[8192 + row] = s2 + (logZo - logZm);
  }
}

// single-block final reduce of 2x8192 partials -> scalar loss
__global__ __launch_bounds__(1024) void loss_fin(const float* __restrict__ partial,
                                                 float* __restrict__ out) {
  __shared__ float sm[32];
  const int t = threadIdx.x;
  float a = 0.f, b = 0.f;
  for (int i = t; i < 8192; i += 1024) {
    a += partial[i];
    b += partial[8192 + i];
  }
  float v = a + b;
#pragma unroll
  for (int o = 32; o > 0; o >>= 1) v += __shfl_xor(v, o);
  if ((t & 63) == 0) sm[t >> 6] = v;
  __syncthreads();
  if (t == 0) {
    float s = 0.f;
#pragma unroll
    for (int w = 0; w < 16; ++w) s += sm[w];
    out[0] = 0.125f * s;  // 0.5*(kl1+kl2)/B, B=4
  }
}

// ---------------------------------------------------------------------------
extern "C" void kernel_launch(void* const* d_in, const int* in_sizes, int n_in,
                              void* d_out, int out_size, void* d_ws, size_t ws_size,
                              hipStream_t stream) {
  const float* x  = (const float*)d_in[0];
  const float* pe = (const float*)d_in[1];
  const float* a1 = (const float*)d_in[2];
  const float* w1 = (const float*)d_in[3];
  const float* b1 = (const float*)d_in[4];
  const float* a2 = (const float*)d_in[5];
  const float* w2 = (const float*)d_in[6];
  const float* b2 = (const float*)d_in[7];
  const float* a3 = (const float*)d_in[8];
  const float* w3 = (const float*)d_in[9];
  const float* b3 = (const float*)d_in[10];
  const float* Wq = (const float*)d_in[11];
  const float* Wk = (const float*)d_in[12];
  const float* Wv = (const float*)d_in[13];
  const float* Wp = (const float*)d_in[14];
  const float* bp = (const float*)d_in[15];
  const float* We = (const float*)d_in[16];
  const float* be = (const float*)d_in[17];
  const float* Wc = (const float*)d_in[18];
  const float* bc = (const float*)d_in[19];
  float* out = (float*)d_out;

  char* ws = (char*)d_ws;
  float* prior  = (float*)(ws + 0);              // 33.55 MB fp32
  bf16*  xn     = (bf16*)(ws + 33554432ull);     // 16.78 MB bf16 (reused: attn out)
  bf16*  Qb     = (bf16*)(ws + 50331648ull);     // (reused: h2)
  bf16*  Kb     = (bf16*)(ws + 67108864ull);
  bf16*  Vb     = (bf16*)(ws + 83886080ull);
  bf16*  Vt     = (bf16*)(ws + 100663296ull);
  float* scores = (float*)(ws + 117440512ull);   // 67.1 MB fp32 (reused: eb bf16, then loss partials)
  bf16*  Wqb    = (bf16*)(ws + 184549376ull);
  bf16*  Wkb    = (bf16*)(ws + 186646528ull);
  bf16*  Wvb    = (bf16*)(ws + 188743680ull);
  bf16*  Wpb    = (bf16*)(ws + 190840832ull);
  bf16*  Web    = (bf16*)(ws + 192937984ull);
  bf16*  Wcb    = (bf16*)(ws + 201326592ull);
  bf16*  attno  = xn;
  bf16*  h2     = Qb;
  bf16*  eb     = (bf16*)scores;
  float* partial = (float*)(ws + 117440512ull);  // 64 KB, reuses dead eb region
  bf16*  probs  = (bf16*)d_out;  // 33,554,432 B <= out buffer; consumed before posterior write

  dim3 blk(256);

  conv_w<<<dim3(1024, 6), blk, 0, stream>>>(Wq, Wk, Wv, Wp, We, Wc,
                                            Wqb, Wkb, Wvb, Wpb, Web, Wcb,
                                            1048576, 1048576, 1048576, 1048576, 4194304, 4194304);
  ew_pre<<<2048, blk, 0, stream>>>(x, pe, a1, w1, b1, a3, w3, b3, prior, xn, 2097152);

  // QKV: [8192,1024] = xn @ W^T
  gemm_bt<EPI_BF16><<<dim3(8, 64, 1), blk, 0, stream>>>(xn, Wqb, Qb, 1024, 1024, 0, 0, 0,
      nullptr, nullptr, nullptr, nullptr, nullptr, 0.f);
  gemm_bt<EPI_BF16><<<dim3(8, 64, 1), blk, 0, stream>>>(xn, Wkb, Kb, 1024, 1024, 0, 0, 0,
      nullptr, nullptr, nullptr, nullptr, nullptr, 0.f);
  gemm_bt<EPI_BF16><<<dim3(8, 64, 1), blk, 0, stream>>>(xn, Wvb, Vb, 1024, 1024, 0, 0, 0,
      nullptr, nullptr, nullptr, nullptr, nullptr, 0.f);
  transpose_k<<<dim3(16, 32, 4), blk, 0, stream>>>(Vb, Vt);

  // scores[b,t,s] = (Q·K)/32 - |t-s|
  gemm_bt<EPI_SCORES><<<dim3(16, 16, 4), blk, 0, stream>>>(Qb, Kb, scores, 2048, 1024,
      2097152ll, 2097152ll, 4194304ll, nullptr, nullptr, nullptr, nullptr, nullptr, 0.03125f);
  softmax_k<<<8192, blk, 0, stream>>>(scores, probs);

  // out[b,t,d] = probs @ V  (B = Vt[b][d][s], K-contiguous)
  gemm_bt<EPI_BF16><<<dim3(8, 16, 4), blk, 0, stream>>>(probs, Vt, attno, 1024, 2048,
      4194304ll, 2097152ll, 2097152ll, nullptr, nullptr, nullptr, nullptr, nullptr, 0.f);

  // proj + dyt2
  gemm_bt<EPI_DYT><<<dim3(8, 64, 1), blk, 0, stream>>>(attno, Wpb, h2, 1024, 1024, 0, 0, 0,
      bp, a2, w2, b2, nullptr, 0.f);
  // expand + exact gelu
  gemm_bt<EPI_GELU><<<dim3(32, 64, 1), blk, 0, stream>>>(h2, Web, eb, 4096, 1024, 0, 0, 0,
      be, nullptr, nullptr, nullptr, nullptr, 0.f);
  // contract + bias + prior -> posterior (fp32, d_out)
  gemm_bt<EPI_PRIOR><<<dim3(8, 64, 1), blk, 0, stream>>>(eb, Wcb, out, 1024, 4096, 0, 0, 0,
      bc, nullptr, nullptr, nullptr, prior, 0.f);

  // JS loss: per-row partials then single-block reduce (no same-address atomics)
  loss_k<<<8192, blk, 0, stream>>>(prior, out, partial);
  loss_fin<<<1, 1024, 0, stream>>>(partial, out + 8388608);
}

// Round 3
// 508.171 us; speedup vs baseline: 1.4419x; 1.0493x over previous
//
#include <hip/hip_runtime.h>
#include <cstdint>
#include <cstddef>

typedef __bf16 bf16;
typedef __bf16 bf16x4 __attribute__((ext_vector_type(4)));
typedef __bf16 bf16x8 __attribute__((ext_vector_type(8)));
typedef float  f32x4 __attribute__((ext_vector_type(4)));

#define DEVI __device__ __forceinline__

// ---------------------------------------------------------------------------
// async global->LDS (16B per lane), CK-style address-space casts
// ---------------------------------------------------------------------------
DEVI void async_ld16(void* lds, const void* g) {
  const __attribute__((address_space(1))) uint32_t* g1 =
      reinterpret_cast<const __attribute__((address_space(1))) uint32_t*>(
          reinterpret_cast<uintptr_t>(g));
  uint32_t lo = (uint32_t)reinterpret_cast<uintptr_t>(lds);
  __attribute__((address_space(3))) uint32_t* l3 =
      reinterpret_cast<__attribute__((address_space(3))) uint32_t*>(lo);
  __builtin_amdgcn_global_load_lds(g1, l3, 16, 0, 0);
}

enum { EPI_BF16 = 0, EPI_QKV = 1, EPI_SCORES = 2, EPI_DYT = 3, EPI_GELU = 4, EPI_PRIOR = 5 };

// ---------------------------------------------------------------------------
// B^T GEMM: C[row,col] = sum_k A[row,k]*B[col,k]  (both K-contiguous)
// 128x128 tile, BK=64, 4 waves; m97 structure + T1 XCD-chunked block swizzle.
// All grids MUST be a multiple of 8 blocks (they are: 1536/1024/512/2048).
// ---------------------------------------------------------------------------
template <int EPI>
__global__ __launch_bounds__(256, 2) void gemm_bt(
    const bf16* __restrict__ A, const bf16* __restrict__ Bm, void* __restrict__ Cv,
    int N, int K,
    long long bsA, long long bsB, long long bsC,
    const float* __restrict__ bias, const float* __restrict__ al,
    const float* __restrict__ wv, const float* __restrict__ bv,
    const float* __restrict__ prior, float scale)
{
  __shared__ __align__(16) bf16 As[128 * 64];
  __shared__ __align__(16) bf16 Bs[128 * 64];
  const int tid = threadIdx.x;

  // T1: XCD-chunked swizzle. HW block h runs on XCD h%8; give each XCD a
  // contiguous chunk of logical tiles so A-panel sharers co-reside per-XCD L2.
  const int gx = gridDim.x, gy = gridDim.y;
  const int nwg = gx * gy * gridDim.z;
  int id = (blockIdx.z * gy + blockIdx.y) * gx + blockIdx.x;
  id = (id & 7) * (nwg >> 3) + (id >> 3);
  const int bx = id % gx;
  const int t1 = id / gx;
  const int by = t1 % gy;
  const int bz = t1 / gy;

  const bf16* Ab = A  + (size_t)bz * bsA + (size_t)by * 128 * K;
  const bf16* Bb = Bm + (size_t)bz * bsB + (size_t)bx * 128 * K;

  const int lane = tid & 63;
  const int wid  = tid >> 6;
  const int wr = (wid >> 1) * 64;
  const int wc = (wid & 1) * 64;
  const int l15 = lane & 15;
  const int lhi = lane >> 4;

  f32x4 acc[4][4];
  const f32x4 zero = {0.f, 0.f, 0.f, 0.f};
#pragma unroll
  for (int i = 0; i < 4; ++i)
#pragma unroll
    for (int j = 0; j < 4; ++j) acc[i][j] = zero;

  const int srow = tid >> 3;        // 32 rows per 256-chunk
  const int skk  = (tid & 7) << 3;  // 8 k-elems per 16B

  for (int kt = 0; kt < K; kt += 64) {
#pragma unroll
    for (int it = 0; it < 4; ++it) {
      const int row = srow + it * 32;
      async_ld16(&As[row * 64 + skk], Ab + (size_t)row * K + kt + skk);
    }
#pragma unroll
    for (int it = 0; it < 4; ++it) {
      const int row = srow + it * 32;
      async_ld16(&Bs[row * 64 + skk], Bb + (size_t)row * K + kt + skk);
    }
    asm volatile("s_waitcnt vmcnt(0)" ::: "memory");
    __syncthreads();
#pragma unroll
    for (int ks = 0; ks < 2; ++ks) {
      const int kb = ks * 32 + lhi * 8;
      bf16x8 af[4], bfv[4];
#pragma unroll
      for (int m = 0; m < 4; ++m)
        af[m] = *(const bf16x8*)&As[(wr + m * 16 + l15) * 64 + kb];
#pragma unroll
      for (int n = 0; n < 4; ++n)
        bfv[n] = *(const bf16x8*)&Bs[(wc + n * 16 + l15) * 64 + kb];
#pragma unroll
      for (int m = 0; m < 4; ++m)
#pragma unroll
        for (int n = 0; n < 4; ++n)
          acc[m][n] = __builtin_amdgcn_mfma_f32_16x16x32_bf16(af[m], bfv[n], acc[m][n], 0, 0, 0);
    }
    __syncthreads();
  }

  // epilogue: C/D layout col = lane&15, row = (lane>>4)*4 + reg
  const int crow0 = by * 128 + wr + (lhi << 2);
  const int ccol0 = bx * 128 + wc + l15;

  float a2 = 0.f;
  if constexpr (EPI == EPI_DYT) a2 = al[0];

#pragma unroll
  for (int n = 0; n < 4; ++n) {
    const int col = ccol0 + n * 16;
    float bcol = 0.f, wcol = 0.f, bvcol = 0.f;
    if constexpr (EPI == EPI_DYT || EPI == EPI_GELU || EPI == EPI_PRIOR) bcol = bias[col];
    if constexpr (EPI == EPI_DYT) { wcol = wv[col]; bvcol = bv[col]; }
#pragma unroll
    for (int m = 0; m < 4; ++m) {
#pragma unroll
      for (int r = 0; r < 4; ++r) {
        const int row = crow0 + m * 16 + r;
        const float v = acc[m][n][r];
        if constexpr (EPI == EPI_BF16) {
          bf16* C = (bf16*)Cv + (size_t)bz * bsC;
          C[(size_t)row * N + col] = (bf16)v;
        } else if constexpr (EPI == EPI_QKV) {
          // fused QKV: col 0..3071 -> tensor col>>10 (Q/K/V), inner col&1023
          bf16* C = (bf16*)Cv + (size_t)(col >> 10) * bsC;
          C[(size_t)row * 1024 + (col & 1023)] = (bf16)v;
        } else if constexpr (EPI == EPI_SCORES) {
          float* C = (float*)Cv + (size_t)bz * bsC;
          C[(size_t)row * N + col] = v * scale - fabsf((float)(row - col));
        } else if constexpr (EPI == EPI_DYT) {
          bf16* C = (bf16*)Cv + (size_t)bz * bsC;
          C[(size_t)row * N + col] = (bf16)(tanhf(a2 * (v + bcol)) * wcol + bvcol);
        } else if constexpr (EPI == EPI_GELU) {
          bf16* C = (bf16*)Cv + (size_t)bz * bsC;
          const float g = v + bcol;
          C[(size_t)row * N + col] = (bf16)(0.5f * g * (1.0f + erff(g * 0.70710678118654752f)));
        } else {  // EPI_PRIOR: fp32 posterior = h + b + prior
          float* C = (float*)Cv;
          C[(size_t)row * N + col] = v + bcol + prior[(size_t)row * N + col];
        }
      }
    }
  }
}

// ---------------------------------------------------------------------------
// fused: xpe = x + pos_embed; prior = dyt3(xpe) (fp32); xn = dyt1(xpe) (bf16)
// ---------------------------------------------------------------------------
__global__ __launch_bounds__(256) void ew_pre(
    const float* __restrict__ x, const float* __restrict__ pe,
    const float* __restrict__ a1p, const float* __restrict__ w1, const float* __restrict__ b1,
    const float* __restrict__ a3p, const float* __restrict__ w3, const float* __restrict__ b3,
    float* __restrict__ prior, bf16* __restrict__ xn, int total4)
{
  const float a1 = a1p[0], a3 = a3p[0];
  for (int i = blockIdx.x * 256 + threadIdx.x; i < total4; i += gridDim.x * 256) {
    const int dq = i & 255;  // D/4 = 256
    const float4 xv  = ((const float4*)x)[i];
    const float4 pv  = ((const float4*)pe)[dq];
    const float4 w1v = ((const float4*)w1)[dq];
    const float4 b1v = ((const float4*)b1)[dq];
    const float4 w3v = ((const float4*)w3)[dq];
    const float4 b3v = ((const float4*)b3)[dq];
    const float x0 = xv.x + pv.x, x1 = xv.y + pv.y, x2 = xv.z + pv.z, x3 = xv.w + pv.w;
    float4 prv;
    prv.x = tanhf(a3 * x0) * w3v.x + b3v.x;
    prv.y = tanhf(a3 * x1) * w3v.y + b3v.y;
    prv.z = tanhf(a3 * x2) * w3v.z + b3v.z;
    prv.w = tanhf(a3 * x3) * w3v.w + b3v.w;
    ((float4*)prior)[i] = prv;
    bf16x4 o;
    o[0] = (bf16)(tanhf(a1 * x0) * w1v.x + b1v.x);
    o[1] = (bf16)(tanhf(a1 * x1) * w1v.y + b1v.y);
    o[2] = (bf16)(tanhf(a1 * x2) * w1v.z + b1v.z);
    o[3] = (bf16)(tanhf(a1 * x3) * w1v.w + b1v.w);
    ((bf16x4*)xn)[i] = o;
  }
}

// fp32 -> bf16 weight conversion, 6 segments via blockIdx.y
__global__ __launch_bounds__(256) void conv_w(
    const float* __restrict__ s0, const float* __restrict__ s1, const float* __restrict__ s2,
    const float* __restrict__ s3, const float* __restrict__ s4, const float* __restrict__ s5,
    bf16* __restrict__ d0, bf16* __restrict__ d1, bf16* __restrict__ d2,
    bf16* __restrict__ d3, bf16* __restrict__ d4, bf16* __restrict__ d5,
    int n0, int n1, int n2, int n3, int n4, int n5)
{
  const float* s; bf16* d; int n;
  switch (blockIdx.y) {
    case 0: s = s0; d = d0; n = n0; break;
    case 1: s = s1; d = d1; n = n1; break;
    case 2: s = s2; d = d2; n = n2; break;
    case 3: s = s3; d = d3; n = n3; break;
    case 4: s = s4; d = d4; n = n4; break;
    default: s = s5; d = d5; n = n5; break;
  }
  const int nq = n >> 2;
  for (int i = blockIdx.x * 256 + threadIdx.x; i < nq; i += gridDim.x * 256) {
    const float4 v = ((const float4*)s)[i];
    bf16x4 o;
    o[0] = (bf16)v.x; o[1] = (bf16)v.y; o[2] = (bf16)v.z; o[3] = (bf16)v.w;
    ((bf16x4*)d)[i] = o;
  }
}

// V [B][T][D] -> Vt [B][D][T], 64x64 LDS tiles
__global__ __launch_bounds__(256) void transpose_k(const bf16* __restrict__ in, bf16* __restrict__ out) {
  __shared__ bf16 tile[64][65];
  const int bx = blockIdx.x;  // D/64
  const int by = blockIdx.y;  // T/64
  const int bz = blockIdx.z;
  const bf16* ib = in  + (size_t)bz * 2048 * 1024;
  bf16* ob       = out + (size_t)bz * 1024 * 2048;
  const int tx = threadIdx.x & 15, ty = threadIdx.x >> 4;
#pragma unroll
  for (int i = 0; i < 4; ++i) {
    const int r = ty + i * 16;
    const bf16x4 v = *(const bf16x4*)(ib + (size_t)(by * 64 + r) * 1024 + bx * 64 + tx * 4);
    tile[r][tx * 4 + 0] = v[0]; tile[r][tx * 4 + 1] = v[1];
    tile[r][tx * 4 + 2] = v[2]; tile[r][tx * 4 + 3] = v[3];
  }
  __syncthreads();
#pragma unroll
  for (int i = 0; i < 4; ++i) {
    const int r = ty + i * 16;   // d_local
    const int c = tx * 4;        // t_local
    bf16x4 v;
    v[0] = tile[c + 0][r]; v[1] = tile[c + 1][r];
    v[2] = tile[c + 2][r]; v[3] = tile[c + 3][r];
    *(bf16x4*)(ob + (size_t)(bx * 64 + r) * 2048 + by * 64 + c) = v;
  }
}

// ---------------------------------------------------------------------------
// reductions
// ---------------------------------------------------------------------------
DEVI float wave_red_max(float v) {
#pragma unroll
  for (int o = 32; o > 0; o >>= 1) v = fmaxf(v, __shfl_xor(v, o));
  return v;
}
DEVI float wave_red_sum(float v) {
#pragma unroll
  for (int o = 32; o > 0; o >>= 1) v += __shfl_xor(v, o);
  return v;
}
DEVI float block_red_max(float v, float* sm) {
  v = wave_red_max(v);
  if ((threadIdx.x & 63) == 0) sm[threadIdx.x >> 6] = v;
  __syncthreads();
  v = fmaxf(fmaxf(sm[0], sm[1]), fmaxf(sm[2], sm[3]));
  __syncthreads();
  return v;
}
DEVI float block_red_sum(float v, float* sm) {
  v = wave_red_sum(v);
  if ((threadIdx.x & 63) == 0) sm[threadIdx.x >> 6] = v;
  __syncthreads();
  v = sm[0] + sm[1] + sm[2] + sm[3];
  __syncthreads();
  return v;
}

// row softmax over 2048 scores (fp32 in) -> bf16 probs
__global__ __launch_bounds__(256) void softmax_k(const float* __restrict__ scores, bf16* __restrict__ probs) {
  __shared__ float sm[4];
  const size_t row = blockIdx.x;
  const float* s = scores + row * 2048;
  bf16* p = probs + row * 2048;
  const int t = threadIdx.x;
  const float4 v0 = *(const float4*)&s[t * 4];
  const float4 v1 = *(const float4*)&s[1024 + t * 4];
  float mx = fmaxf(fmaxf(fmaxf(v0.x, v0.y), fmaxf(v0.z, v0.w)),
                   fmaxf(fmaxf(v1.x, v1.y), fmaxf(v1.z, v1.w)));
  mx = block_red_max(mx, sm);
  const float e0 = expf(v0.x - mx), e1 = expf(v0.y - mx), e2 = expf(v0.z - mx), e3 = expf(v0.w - mx);
  const float e4 = expf(v1.x - mx), e5 = expf(v1.y - mx), e6 = expf(v1.z - mx), e7 = expf(v1.w - mx);
  float ssum = e0 + e1 + e2 + e3 + e4 + e5 + e6 + e7;
  ssum = block_red_sum(ssum, sm);
  const float inv = 1.0f / ssum;
  bf16x4 o0, o1;
  o0[0] = (bf16)(e0 * inv); o0[1] = (bf16)(e1 * inv); o0[2] = (bf16)(e2 * inv); o0[3] = (bf16)(e3 * inv);
  o1[0] = (bf16)(e4 * inv); o1[1] = (bf16)(e5 * inv); o1[2] = (bf16)(e6 * inv); o1[3] = (bf16)(e7 * inv);
  *(bf16x4*)&p[t * 4] = o0;
  *(bf16x4*)&p[1024 + t * 4] = o1;
}

// per-row JS pieces -> per-row partials (NO global atomics; 2-stage reduce)
__global__ __launch_bounds__(256) void loss_k(const float* __restrict__ prior,
                                              const float* __restrict__ post,
                                              float* __restrict__ partial) {
  __shared__ float sm[4];
  const size_t row = blockIdx.x;
  const int t = threadIdx.x;
  const float4 pr = *(const float4*)&prior[row * 1024 + t * 4];
  const float4 po = *(const float4*)&post[row * 1024 + t * 4];
  float4 mm;
  mm.x = 0.5f * (pr.x + po.x); mm.y = 0.5f * (pr.y + po.y);
  mm.z = 0.5f * (pr.z + po.z); mm.w = 0.5f * (pr.w + po.w);
  const float mxp = block_red_max(fmaxf(fmaxf(pr.x, pr.y), fmaxf(pr.z, pr.w)), sm);
  const float mxo = block_red_max(fmaxf(fmaxf(po.x, po.y), fmaxf(po.z, po.w)), sm);
  const float mxm = block_red_max(fmaxf(fmaxf(mm.x, mm.y), fmaxf(mm.z, mm.w)), sm);
  float sp = expf(pr.x - mxp) + expf(pr.y - mxp) + expf(pr.z - mxp) + expf(pr.w - mxp);
  sp = block_red_sum(sp, sm);
  float so = expf(po.x - mxo) + expf(po.y - mxo) + expf(po.z - mxo) + expf(po.w - mxo);
  so = block_red_sum(so, sm);
  const float em0 = expf(mm.x - mxm), em1 = expf(mm.y - mxm), em2 = expf(mm.z - mxm), em3 = expf(mm.w - mxm);
  float smm = block_red_sum(em0 + em1 + em2 + em3, sm);
  const float invm = 1.0f / smm;
  float s1 = em0 * invm * (mm.x - pr.x) + em1 * invm * (mm.y - pr.y) +
             em2 * invm * (mm.z - pr.z) + em3 * invm * (mm.w - pr.w);
  float s2 = em0 * invm * (mm.x - po.x) + em1 * invm * (mm.y - po.y) +
             em2 * invm * (mm.z - po.z) + em3 * invm * (mm.w - po.w);
  s1 = block_red_sum(s1, sm);
  s2 = block_red_sum(s2, sm);
  if (t == 0) {
    const float logZp = mxp + logf(sp);
    const float logZo = mxo + logf(so);
    const float logZm = mxm + logf(smm);
    partial[row]        = s1 + (logZp - logZm);
    partial[8192 + row] = s2 + (logZo - logZm);
  }
}

// single-block final reduce of 2x8192 partials -> scalar loss
__global__ __launch_bounds__(1024) void loss_fin(const float* __restrict__ partial,
                                                 float* __restrict__ out) {
  __shared__ float sm[32];
  const int t = threadIdx.x;
  float a = 0.f, b = 0.f;
  for (int i = t; i < 8192; i += 1024) {
    a += partial[i];
    b += partial[8192 + i];
  }
  float v = a + b;
#pragma unroll
  for (int o = 32; o > 0; o >>= 1) v += __shfl_xor(v, o);
  if ((t & 63) == 0) sm[t >> 6] = v;
  __syncthreads();
  if (t == 0) {
    float s = 0.f;
#pragma unroll
    for (int w = 0; w < 16; ++w) s += sm[w];
    out[0] = 0.125f * s;  // 0.5*(kl1+kl2)/B, B=4
  }
}

// ---------------------------------------------------------------------------
extern "C" void kernel_launch(void* const* d_in, const int* in_sizes, int n_in,
                              void* d_out, int out_size, void* d_ws, size_t ws_size,
                              hipStream_t stream) {
  const float* x  = (const float*)d_in[0];
  const float* pe = (const float*)d_in[1];
  const float* a1 = (const float*)d_in[2];
  const float* w1 = (const float*)d_in[3];
  const float* b1 = (const float*)d_in[4];
  const float* a2 = (const float*)d_in[5];
  const float* w2 = (const float*)d_in[6];
  const float* b2 = (const float*)d_in[7];
  const float* a3 = (const float*)d_in[8];
  const float* w3 = (const float*)d_in[9];
  const float* b3 = (const float*)d_in[10];
  const float* Wq = (const float*)d_in[11];
  const float* Wk = (const float*)d_in[12];
  const float* Wv = (const float*)d_in[13];
  const float* Wp = (const float*)d_in[14];
  const float* bp = (const float*)d_in[15];
  const float* We = (const float*)d_in[16];
  const float* be = (const float*)d_in[17];
  const float* Wc = (const float*)d_in[18];
  const float* bc = (const float*)d_in[19];
  float* out = (float*)d_out;

  char* ws = (char*)d_ws;
  float* prior  = (float*)(ws + 0);              // 33.55 MB fp32
  bf16*  xn     = (bf16*)(ws + 33554432ull);     // 16.78 MB bf16 (reused: attn out)
  bf16*  Qb     = (bf16*)(ws + 50331648ull);     // (reused: h2)
  bf16*  Kb     = (bf16*)(ws + 67108864ull);
  bf16*  Vb     = (bf16*)(ws + 83886080ull);
  bf16*  Vt     = (bf16*)(ws + 100663296ull);
  float* scores = (float*)(ws + 117440512ull);   // 67.1 MB fp32 (reused: eb bf16, then loss partials)
  bf16*  Wqb    = (bf16*)(ws + 184549376ull);    // Wqb/Wkb/Wvb contiguous = fused [3072,1024]
  bf16*  Wkb    = (bf16*)(ws + 186646528ull);
  bf16*  Wvb    = (bf16*)(ws + 188743680ull);
  bf16*  Wpb    = (bf16*)(ws + 190840832ull);
  bf16*  Web    = (bf16*)(ws + 192937984ull);
  bf16*  Wcb    = (bf16*)(ws + 201326592ull);
  bf16*  attno  = xn;
  bf16*  h2     = Qb;
  bf16*  eb     = (bf16*)scores;
  float* partial = (float*)(ws + 117440512ull);  // 64 KB, reuses dead eb region
  bf16*  probs  = (bf16*)d_out;  // 33,554,432 B <= out buffer; consumed before posterior write

  dim3 blk(256);

  conv_w<<<dim3(1024, 6), blk, 0, stream>>>(Wq, Wk, Wv, Wp, We, Wc,
                                            Wqb, Wkb, Wvb, Wpb, Web, Wcb,
                                            1048576, 1048576, 1048576, 1048576, 4194304, 4194304);
  ew_pre<<<2048, blk, 0, stream>>>(x, pe, a1, w1, b1, a3, w3, b3, prior, xn, 2097152);

  // fused QKV: [8192,3072] = xn @ [Wq;Wk;Wv]^T, split into Q/K/V on store
  gemm_bt<EPI_QKV><<<dim3(24, 64, 1), blk, 0, stream>>>(xn, Wqb, Qb, 3072, 1024, 0, 0,
      8388608ll /* elements per tensor */, nullptr, nullptr, nullptr, nullptr, nullptr, 0.f);
  transpose_k<<<dim3(16, 32, 4), blk, 0, stream>>>(Vb, Vt);

  // scores[b,t,s] = (Q·K)/32 - |t-s|
  gemm_bt<EPI_SCORES><<<dim3(16, 16, 4), blk, 0, stream>>>(Qb, Kb, scores, 2048, 1024,
      2097152ll, 2097152ll, 4194304ll, nullptr, nullptr, nullptr, nullptr, nullptr, 0.03125f);
  softmax_k<<<8192, blk, 0, stream>>>(scores, probs);

  // out[b,t,d] = probs @ V  (B = Vt[b][d][s], K-contiguous)
  gemm_bt<EPI_BF16><<<dim3(8, 16, 4), blk, 0, stream>>>(probs, Vt, attno, 1024, 2048,
      4194304ll, 2097152ll, 2097152ll, nullptr, nullptr, nullptr, nullptr, nullptr, 0.f);

  // proj + dyt2
  gemm_bt<EPI_DYT><<<dim3(8, 64, 1), blk, 0, stream>>>(attno, Wpb, h2, 1024, 1024, 0, 0, 0,
      bp, a2, w2, b2, nullptr, 0.f);
  // expand + exact gelu
  gemm_bt<EPI_GELU><<<dim3(32, 64, 1), blk, 0, stream>>>(h2, Web, eb, 4096, 1024, 0, 0, 0,
      be, nullptr, nullptr, nullptr, nullptr, 0.f);
  // contract + bias + prior -> posterior (fp32, d_out)
  gemm_bt<EPI_PRIOR><<<dim3(8, 64, 1), blk, 0, stream>>>(eb, Wcb, out, 1024, 4096, 0, 0, 0,
      bc, nullptr, nullptr, nullptr, prior, 0.f);

  // JS loss: per-row partials then single-block reduce (no same-address atomics)
  loss_k<<<8192, blk, 0, stream>>>(prior, out, partial);
  loss_fin<<<1, 1024, 0, stream>>>(partial, out + 8388608);
}

// Round 4
// 483.919 us; speedup vs baseline: 1.5142x; 1.0501x over previous
//
#include <hip/hip_runtime.h>
#include <cstdint>
#include <cstddef>

typedef __bf16 bf16;
typedef __bf16 bf16x4 __attribute__((ext_vector_type(4)));
typedef __bf16 bf16x8 __attribute__((ext_vector_type(8)));
typedef float  f32x4 __attribute__((ext_vector_type(4)));

#define DEVI __device__ __forceinline__

// ---------------------------------------------------------------------------
// async global->LDS (16B per lane)
// ---------------------------------------------------------------------------
DEVI void async_ld16(void* lds, const void* g) {
  const __attribute__((address_space(1))) uint32_t* g1 =
      reinterpret_cast<const __attribute__((address_space(1))) uint32_t*>(
          reinterpret_cast<uintptr_t>(g));
  uint32_t lo = (uint32_t)reinterpret_cast<uintptr_t>(lds);
  __attribute__((address_space(3))) uint32_t* l3 =
      reinterpret_cast<__attribute__((address_space(3))) uint32_t*>(lo);
  __builtin_amdgcn_global_load_lds(g1, l3, 16, 0, 0);
}

template <int N> DEVI void wait_vmcnt() {
  asm volatile("s_waitcnt vmcnt(%0)" :: "n"(N) : "memory");
}
DEVI void blk_barrier() {
  asm volatile("" ::: "memory");
  __builtin_amdgcn_s_barrier();
  asm volatile("" ::: "memory");
}

enum { EPI_BF16 = 0, EPI_QKV = 1, EPI_SCORES = 2, EPI_DYT = 3, EPI_GELU = 4, EPI_PRIOR = 5 };

// ---------------------------------------------------------------------------
// B^T GEMM, deep-pipelined: C[row,col] = sum_k A[row,k]*B[col,k]
// BN=256, BK=32, BM in {128,256}. 8 waves (2Mx4N), 512 threads.
// 4-deep LDS ring, counted vmcnt (never 0 in main loop), raw s_barrier,
// setprio around MFMA cluster. LDS rows are 64B => all ds_read_b128
// fragment reads are contiguous 1KB per wave: bank-conflict-free.
// Grids are exact multiples of 8 (XCD-chunked swizzle).
// ---------------------------------------------------------------------------
template <int BM, int EPI>
__global__ __launch_bounds__(512, 2) void gemm2(
    const bf16* __restrict__ A, const bf16* __restrict__ Bm, void* __restrict__ Cv,
    int N, int K,
    long long bsA, long long bsB, long long bsC,
    const float* __restrict__ bias, const float* __restrict__ al,
    const float* __restrict__ wv, const float* __restrict__ bv,
    const float* __restrict__ prior, float scale)
{
  constexpr int BN = 256;
  constexpr int BK = 32;
  constexpr int ASZ = BM * BK;                       // elems
  constexpr int BSZ = BN * BK;
  constexpr int SLOT = ASZ + BSZ;                    // elems per ring slot
  constexpr int LOADS_A = (BM * BK * 2) / (512 * 16);  // 1 (BM=128) or 2 (BM=256)
  constexpr int L = LOADS_A + 2;                     // loads per tile per wave
  constexpr int MF = BM / 32;                        // m-frags per wave

  extern __shared__ __align__(16) bf16 smem[];       // 4 * SLOT elems

  const int tid = threadIdx.x;

  // T1 XCD-chunked swizzle (nwg always a multiple of 8)
  const int gx = gridDim.x, gy = gridDim.y;
  const int nwg = gx * gy * gridDim.z;
  int id = (blockIdx.z * gy + blockIdx.y) * gx + blockIdx.x;
  id = (id & 7) * (nwg >> 3) + (id >> 3);
  const int bx = id % gx;
  const int t1 = id / gx;
  const int by = t1 % gy;
  const int bz = t1 / gy;

  const bf16* Ab = A  + (size_t)bz * bsA + (size_t)by * BM * K;
  const bf16* Bb = Bm + (size_t)bz * bsB + (size_t)bx * BN * K;

  const int lane = tid & 63;
  const int wid  = tid >> 6;
  const int l15 = lane & 15;
  const int lhi = lane >> 4;
  const int wr = (wid >> 2) * (BM / 2);   // wave row block
  const int wc = (wid & 3) * 64;          // wave col block

  const int sa_row = tid >> 2;            // 0..127
  const int sa_off = (tid & 3) * 8;       // k-elem offset (16B)

  f32x4 acc[MF][4];
  const f32x4 zero = {0.f, 0.f, 0.f, 0.f};
#pragma unroll
  for (int m = 0; m < MF; ++m)
#pragma unroll
    for (int n = 0; n < 4; ++n) acc[m][n] = zero;

  const int NT = K / BK;  // >= 32 for all our shapes

  auto STAGE = [&](int t) {
    bf16* dst = smem + (size_t)(t & 3) * SLOT;
    const size_t kb = (size_t)t * BK;
#pragma unroll
    for (int i = 0; i < LOADS_A; ++i) {
      const int row = sa_row + i * 128;
      async_ld16(dst + row * BK + sa_off, Ab + (size_t)row * K + kb + sa_off);
    }
#pragma unroll
    for (int i = 0; i < 2; ++i) {
      const int row = sa_row + i * 128;
      async_ld16(dst + ASZ + row * BK + sa_off, Bb + (size_t)row * K + kb + sa_off);
    }
  };

  auto COMPUTE = [&](int t) {
    const bf16* buf = smem + (size_t)(t & 3) * SLOT;
    bf16x8 bf_[4], af_[MF];
#pragma unroll
    for (int n = 0; n < 4; ++n)
      bf_[n] = *(const bf16x8*)&buf[ASZ + (wc + n * 16 + l15) * BK + lhi * 8];
#pragma unroll
    for (int m = 0; m < MF; ++m)
      af_[m] = *(const bf16x8*)&buf[(wr + m * 16 + l15) * BK + lhi * 8];
    __builtin_amdgcn_s_setprio(1);
#pragma unroll
    for (int m = 0; m < MF; ++m)
#pragma unroll
      for (int n = 0; n < 4; ++n)
        acc[m][n] = __builtin_amdgcn_mfma_f32_16x16x32_bf16(af_[m], bf_[n], acc[m][n], 0, 0, 0);
    __builtin_amdgcn_s_setprio(0);
  };

  // prologue: 3 tiles in flight
  STAGE(0); STAGE(1); STAGE(2);

  // main loop: stage t+3 (into the slot whose reads finished at the barrier
  // ending iteration t-1), wait only for tile t (3 tiles stay in flight)
  for (int t = 0; t < NT - 3; ++t) {
    STAGE(t + 3);
    wait_vmcnt<3 * L>();
    blk_barrier();
    COMPUTE(t);
    blk_barrier();
  }
  wait_vmcnt<2 * L>(); blk_barrier(); COMPUTE(NT - 3); blk_barrier();
  wait_vmcnt<1 * L>(); blk_barrier(); COMPUTE(NT - 2); blk_barrier();
  wait_vmcnt<0>();     blk_barrier(); COMPUTE(NT - 1);

  // epilogue: C/D layout col = lane&15, row = (lane>>4)*4 + reg
  const int crow0 = by * BM + wr + (lhi << 2);
  const int ccol0 = bx * BN + wc + l15;

  float a2 = 0.f;
  if constexpr (EPI == EPI_DYT) a2 = al[0];

#pragma unroll
  for (int n = 0; n < 4; ++n) {
    const int col = ccol0 + n * 16;
    float bcol = 0.f, wcol = 0.f, bvcol = 0.f;
    if constexpr (EPI == EPI_DYT || EPI == EPI_GELU || EPI == EPI_PRIOR) bcol = bias[col];
    if constexpr (EPI == EPI_DYT) { wcol = wv[col]; bvcol = bv[col]; }
#pragma unroll
    for (int m = 0; m < MF; ++m) {
#pragma unroll
      for (int r = 0; r < 4; ++r) {
        const int row = crow0 + m * 16 + r;
        const float v = acc[m][n][r];
        if constexpr (EPI == EPI_BF16) {
          bf16* C = (bf16*)Cv + (size_t)bz * bsC;
          C[(size_t)row * N + col] = (bf16)v;
        } else if constexpr (EPI == EPI_QKV) {
          bf16* C = (bf16*)Cv + (size_t)(col >> 10) * bsC;
          C[(size_t)row * 1024 + (col & 1023)] = (bf16)v;
        } else if constexpr (EPI == EPI_SCORES) {
          float* C = (float*)Cv + (size_t)bz * bsC;
          C[(size_t)row * N + col] = v * scale - fabsf((float)(row - col));
        } else if constexpr (EPI == EPI_DYT) {
          bf16* C = (bf16*)Cv + (size_t)bz * bsC;
          C[(size_t)row * N + col] = (bf16)(tanhf(a2 * (v + bcol)) * wcol + bvcol);
        } else if constexpr (EPI == EPI_GELU) {
          bf16* C = (bf16*)Cv + (size_t)bz * bsC;
          const float g = v + bcol;
          C[(size_t)row * N + col] = (bf16)(0.5f * g * (1.0f + erff(g * 0.70710678118654752f)));
        } else {  // EPI_PRIOR
          float* C = (float*)Cv;
          C[(size_t)row * N + col] = v + bcol + prior[(size_t)row * N + col];
        }
      }
    }
  }
}

// ---------------------------------------------------------------------------
// fused: xpe = x + pos_embed; prior = dyt3(xpe) (fp32); xn = dyt1(xpe) (bf16)
// ---------------------------------------------------------------------------
__global__ __launch_bounds__(256) void ew_pre(
    const float* __restrict__ x, const float* __restrict__ pe,
    const float* __restrict__ a1p, const float* __restrict__ w1, const float* __restrict__ b1,
    const float* __restrict__ a3p, const float* __restrict__ w3, const float* __restrict__ b3,
    float* __restrict__ prior, bf16* __restrict__ xn, int total4)
{
  const float a1 = a1p[0], a3 = a3p[0];
  for (int i = blockIdx.x * 256 + threadIdx.x; i < total4; i += gridDim.x * 256) {
    const int dq = i & 255;
    const float4 xv  = ((const float4*)x)[i];
    const float4 pv  = ((const float4*)pe)[dq];
    const float4 w1v = ((const float4*)w1)[dq];
    const float4 b1v = ((const float4*)b1)[dq];
    const float4 w3v = ((const float4*)w3)[dq];
    const float4 b3v = ((const float4*)b3)[dq];
    const float x0 = xv.x + pv.x, x1 = xv.y + pv.y, x2 = xv.z + pv.z, x3 = xv.w + pv.w;
    float4 prv;
    prv.x = tanhf(a3 * x0) * w3v.x + b3v.x;
    prv.y = tanhf(a3 * x1) * w3v.y + b3v.y;
    prv.z = tanhf(a3 * x2) * w3v.z + b3v.z;
    prv.w = tanhf(a3 * x3) * w3v.w + b3v.w;
    ((float4*)prior)[i] = prv;
    bf16x4 o;
    o[0] = (bf16)(tanhf(a1 * x0) * w1v.x + b1v.x);
    o[1] = (bf16)(tanhf(a1 * x1) * w1v.y + b1v.y);
    o[2] = (bf16)(tanhf(a1 * x2) * w1v.z + b1v.z);
    o[3] = (bf16)(tanhf(a1 * x3) * w1v.w + b1v.w);
    ((bf16x4*)xn)[i] = o;
  }
}

// fp32 -> bf16 weight conversion, 6 segments via blockIdx.y
__global__ __launch_bounds__(256) void conv_w(
    const float* __restrict__ s0, const float* __restrict__ s1, const float* __restrict__ s2,
    const float* __restrict__ s3, const float* __restrict__ s4, const float* __restrict__ s5,
    bf16* __restrict__ d0, bf16* __restrict__ d1, bf16* __restrict__ d2,
    bf16* __restrict__ d3, bf16* __restrict__ d4, bf16* __restrict__ d5,
    int n0, int n1, int n2, int n3, int n4, int n5)
{
  const float* s; bf16* d; int n;
  switch (blockIdx.y) {
    case 0: s = s0; d = d0; n = n0; break;
    case 1: s = s1; d = d1; n = n1; break;
    case 2: s = s2; d = d2; n = n2; break;
    case 3: s = s3; d = d3; n = n3; break;
    case 4: s = s4; d = d4; n = n4; break;
    default: s = s5; d = d5; n = n5; break;
  }
  const int nq = n >> 2;
  for (int i = blockIdx.x * 256 + threadIdx.x; i < nq; i += gridDim.x * 256) {
    const float4 v = ((const float4*)s)[i];
    bf16x4 o;
    o[0] = (bf16)v.x; o[1] = (bf16)v.y; o[2] = (bf16)v.z; o[3] = (bf16)v.w;
    ((bf16x4*)d)[i] = o;
  }
}

// V [B][T][D] -> Vt [B][D][T]
__global__ __launch_bounds__(256) void transpose_k(const bf16* __restrict__ in, bf16* __restrict__ out) {
  __shared__ bf16 tile[64][65];
  const int bx = blockIdx.x;
  const int by = blockIdx.y;
  const int bz = blockIdx.z;
  const bf16* ib = in  + (size_t)bz * 2048 * 1024;
  bf16* ob       = out + (size_t)bz * 1024 * 2048;
  const int tx = threadIdx.x & 15, ty = threadIdx.x >> 4;
#pragma unroll
  for (int i = 0; i < 4; ++i) {
    const int r = ty + i * 16;
    const bf16x4 v = *(const bf16x4*)(ib + (size_t)(by * 64 + r) * 1024 + bx * 64 + tx * 4);
    tile[r][tx * 4 + 0] = v[0]; tile[r][tx * 4 + 1] = v[1];
    tile[r][tx * 4 + 2] = v[2]; tile[r][tx * 4 + 3] = v[3];
  }
  __syncthreads();
#pragma unroll
  for (int i = 0; i < 4; ++i) {
    const int r = ty + i * 16;
    const int c = tx * 4;
    bf16x4 v;
    v[0] = tile[c + 0][r]; v[1] = tile[c + 1][r];
    v[2] = tile[c + 2][r]; v[3] = tile[c + 3][r];
    *(bf16x4*)(ob + (size_t)(bx * 64 + r) * 2048 + by * 64 + c) = v;
  }
}

// ---------------------------------------------------------------------------
// reductions
// ---------------------------------------------------------------------------
DEVI float wave_red_max(float v) {
#pragma unroll
  for (int o = 32; o > 0; o >>= 1) v = fmaxf(v, __shfl_xor(v, o));
  return v;
}
DEVI float wave_red_sum(float v) {
#pragma unroll
  for (int o = 32; o > 0; o >>= 1) v += __shfl_xor(v, o);
  return v;
}
DEVI float block_red_max(float v, float* sm) {
  v = wave_red_max(v);
  if ((threadIdx.x & 63) == 0) sm[threadIdx.x >> 6] = v;
  __syncthreads();
  v = fmaxf(fmaxf(sm[0], sm[1]), fmaxf(sm[2], sm[3]));
  __syncthreads();
  return v;
}
DEVI float block_red_sum(float v, float* sm) {
  v = wave_red_sum(v);
  if ((threadIdx.x & 63) == 0) sm[threadIdx.x >> 6] = v;
  __syncthreads();
  v = sm[0] + sm[1] + sm[2] + sm[3];
  __syncthreads();
  return v;
}

// row softmax over 2048 scores (fp32 in) -> bf16 probs
__global__ __launch_bounds__(256) void softmax_k(const float* __restrict__ scores, bf16* __restrict__ probs) {
  __shared__ float sm[4];
  const size_t row = blockIdx.x;
  const float* s = scores + row * 2048;
  bf16* p = probs + row * 2048;
  const int t = threadIdx.x;
  const float4 v0 = *(const float4*)&s[t * 4];
  const float4 v1 = *(const float4*)&s[1024 + t * 4];
  float mx = fmaxf(fmaxf(fmaxf(v0.x, v0.y), fmaxf(v0.z, v0.w)),
                   fmaxf(fmaxf(v1.x, v1.y), fmaxf(v1.z, v1.w)));
  mx = block_red_max(mx, sm);
  const float e0 = expf(v0.x - mx), e1 = expf(v0.y - mx), e2 = expf(v0.z - mx), e3 = expf(v0.w - mx);
  const float e4 = expf(v1.x - mx), e5 = expf(v1.y - mx), e6 = expf(v1.z - mx), e7 = expf(v1.w - mx);
  float ssum = e0 + e1 + e2 + e3 + e4 + e5 + e6 + e7;
  ssum = block_red_sum(ssum, sm);
  const float inv = 1.0f / ssum;
  bf16x4 o0, o1;
  o0[0] = (bf16)(e0 * inv); o0[1] = (bf16)(e1 * inv); o0[2] = (bf16)(e2 * inv); o0[3] = (bf16)(e3 * inv);
  o1[0] = (bf16)(e4 * inv); o1[1] = (bf16)(e5 * inv); o1[2] = (bf16)(e6 * inv); o1[3] = (bf16)(e7 * inv);
  *(bf16x4*)&p[t * 4] = o0;
  *(bf16x4*)&p[1024 + t * 4] = o1;
}

// per-row JS pieces -> per-row partials
__global__ __launch_bounds__(256) void loss_k(const float* __restrict__ prior,
                                              const float* __restrict__ post,
                                              float* __restrict__ partial) {
  __shared__ float sm[4];
  const size_t row = blockIdx.x;
  const int t = threadIdx.x;
  const float4 pr = *(const float4*)&prior[row * 1024 + t * 4];
  const float4 po = *(const float4*)&post[row * 1024 + t * 4];
  float4 mm;
  mm.x = 0.5f * (pr.x + po.x); mm.y = 0.5f * (pr.y + po.y);
  mm.z = 0.5f * (pr.z + po.z); mm.w = 0.5f * (pr.w + po.w);
  const float mxp = block_red_max(fmaxf(fmaxf(pr.x, pr.y), fmaxf(pr.z, pr.w)), sm);
  const float mxo = block_red_max(fmaxf(fmaxf(po.x, po.y), fmaxf(po.z, po.w)), sm);
  const float mxm = block_red_max(fmaxf(fmaxf(mm.x, mm.y), fmaxf(mm.z, mm.w)), sm);
  float sp = expf(pr.x - mxp) + expf(pr.y - mxp) + expf(pr.z - mxp) + expf(pr.w - mxp);
  sp = block_red_sum(sp, sm);
  float so = expf(po.x - mxo) + expf(po.y - mxo) + expf(po.z - mxo) + expf(po.w - mxo);
  so = block_red_sum(so, sm);
  const float em0 = expf(mm.x - mxm), em1 = expf(mm.y - mxm), em2 = expf(mm.z - mxm), em3 = expf(mm.w - mxm);
  float smm = block_red_sum(em0 + em1 + em2 + em3, sm);
  const float invm = 1.0f / smm;
  float s1 = em0 * invm * (mm.x - pr.x) + em1 * invm * (mm.y - pr.y) +
             em2 * invm * (mm.z - pr.z) + em3 * invm * (mm.w - pr.w);
  float s2 = em0 * invm * (mm.x - po.x) + em1 * invm * (mm.y - po.y) +
             em2 * invm * (mm.z - po.z) + em3 * invm * (mm.w - po.w);
  s1 = block_red_sum(s1, sm);
  s2 = block_red_sum(s2, sm);
  if (t == 0) {
    const float logZp = mxp + logf(sp);
    const float logZo = mxo + logf(so);
    const float logZm = mxm + logf(smm);
    partial[row]        = s1 + (logZp - logZm);
    partial[8192 + row] = s2 + (logZo - logZm);
  }
}

__global__ __launch_bounds__(1024) void loss_fin(const float* __restrict__ partial,
                                                 float* __restrict__ out) {
  __shared__ float sm[32];
  const int t = threadIdx.x;
  float a = 0.f, b = 0.f;
  for (int i = t; i < 8192; i += 1024) {
    a += partial[i];
    b += partial[8192 + i];
  }
  float v = a + b;
#pragma unroll
  for (int o = 32; o > 0; o >>= 1) v += __shfl_xor(v, o);
  if ((t & 63) == 0) sm[t >> 6] = v;
  __syncthreads();
  if (t == 0) {
    float s = 0.f;
#pragma unroll
    for (int w = 0; w < 16; ++w) s += sm[w];
    out[0] = 0.125f * s;
  }
}

// ---------------------------------------------------------------------------
extern "C" void kernel_launch(void* const* d_in, const int* in_sizes, int n_in,
                              void* d_out, int out_size, void* d_ws, size_t ws_size,
                              hipStream_t stream) {
  const float* x  = (const float*)d_in[0];
  const float* pe = (const float*)d_in[1];
  const float* a1 = (const float*)d_in[2];
  const float* w1 = (const float*)d_in[3];
  const float* b1 = (const float*)d_in[4];
  const float* a2 = (const float*)d_in[5];
  const float* w2 = (const float*)d_in[6];
  const float* b2 = (const float*)d_in[7];
  const float* a3 = (const float*)d_in[8];
  const float* w3 = (const float*)d_in[9];
  const float* b3 = (const float*)d_in[10];
  const float* Wq = (const float*)d_in[11];
  const float* Wk = (const float*)d_in[12];
  const float* Wv = (const float*)d_in[13];
  const float* Wp = (const float*)d_in[14];
  const float* bp = (const float*)d_in[15];
  const float* We = (const float*)d_in[16];
  const float* be = (const float*)d_in[17];
  const float* Wc = (const float*)d_in[18];
  const float* bc = (const float*)d_in[19];
  float* out = (float*)d_out;

  char* ws = (char*)d_ws;
  float* prior  = (float*)(ws + 0);
  bf16*  xn     = (bf16*)(ws + 33554432ull);
  bf16*  Qb     = (bf16*)(ws + 50331648ull);
  bf16*  Kb     = (bf16*)(ws + 67108864ull);
  bf16*  Vb     = (bf16*)(ws + 83886080ull);
  bf16*  Vt     = (bf16*)(ws + 100663296ull);
  float* scores = (float*)(ws + 117440512ull);
  bf16*  Wqb    = (bf16*)(ws + 184549376ull);   // Wq/Wk/Wv contiguous
  bf16*  Wkb    = (bf16*)(ws + 186646528ull);
  bf16*  Wvb    = (bf16*)(ws + 188743680ull);
  bf16*  Wpb    = (bf16*)(ws + 190840832ull);
  bf16*  Web    = (bf16*)(ws + 192937984ull);
  bf16*  Wcb    = (bf16*)(ws + 201326592ull);
  bf16*  attno  = xn;
  bf16*  h2     = Qb;
  bf16*  eb     = (bf16*)scores;
  float* partial = (float*)(ws + 117440512ull);
  bf16*  probs  = (bf16*)d_out;

  // dynamic-LDS opt-in (96KB / 128KB > 64KB default)
  static bool attr_done = false;
  if (!attr_done) {
    hipFuncSetAttribute((const void*)gemm2<128, EPI_QKV>,   hipFuncAttributeMaxDynamicSharedMemorySize, 131072);
    hipFuncSetAttribute((const void*)gemm2<256, EPI_SCORES>,hipFuncAttributeMaxDynamicSharedMemorySize, 131072);
    hipFuncSetAttribute((const void*)gemm2<128, EPI_BF16>,  hipFuncAttributeMaxDynamicSharedMemorySize, 131072);
    hipFuncSetAttribute((const void*)gemm2<128, EPI_DYT>,   hipFuncAttributeMaxDynamicSharedMemorySize, 131072);
    hipFuncSetAttribute((const void*)gemm2<256, EPI_GELU>,  hipFuncAttributeMaxDynamicSharedMemorySize, 131072);
    hipFuncSetAttribute((const void*)gemm2<128, EPI_PRIOR>, hipFuncAttributeMaxDynamicSharedMemorySize, 131072);
    attr_done = true;
  }

  dim3 blk(256);
  dim3 gblk(512);
  constexpr unsigned SH128 = 98304;    // (128*32 + 256*32)*2B * 4
  constexpr unsigned SH256 = 131072;   // (256*32 + 256*32)*2B * 4

  conv_w<<<dim3(1024, 6), blk, 0, stream>>>(Wq, Wk, Wv, Wp, We, Wc,
                                            Wqb, Wkb, Wvb, Wpb, Web, Wcb,
                                            1048576, 1048576, 1048576, 1048576, 4194304, 4194304);
  ew_pre<<<2048, blk, 0, stream>>>(x, pe, a1, w1, b1, a3, w3, b3, prior, xn, 2097152);

  // fused QKV: [8192,3072] = xn @ [Wq;Wk;Wv]^T  (768 blocks = 3 full rounds)
  gemm2<128, EPI_QKV><<<dim3(12, 64, 1), gblk, SH128, stream>>>(xn, Wqb, Qb, 3072, 1024,
      0, 0, 8388608ll, nullptr, nullptr, nullptr, nullptr, nullptr, 0.f);
  transpose_k<<<dim3(16, 32, 4), blk, 0, stream>>>(Vb, Vt);

  // scores[b,t,s] = (Q·K)/32 - |t-s|   (256 blocks)
  gemm2<256, EPI_SCORES><<<dim3(8, 8, 4), gblk, SH256, stream>>>(Qb, Kb, scores, 2048, 1024,
      2097152ll, 2097152ll, 4194304ll, nullptr, nullptr, nullptr, nullptr, nullptr, 0.03125f);
  softmax_k<<<8192, blk, 0, stream>>>(scores, probs);

  // out[b,t,d] = probs @ Vt   (256 blocks)
  gemm2<128, EPI_BF16><<<dim3(4, 16, 4), gblk, SH128, stream>>>(probs, Vt, attno, 1024, 2048,
      4194304ll, 2097152ll, 2097152ll, nullptr, nullptr, nullptr, nullptr, nullptr, 0.f);

  // proj + dyt2   (256 blocks)
  gemm2<128, EPI_DYT><<<dim3(4, 64, 1), gblk, SH128, stream>>>(attno, Wpb, h2, 1024, 1024,
      0, 0, 0, bp, a2, w2, b2, nullptr, 0.f);
  // expand + exact gelu   (512 blocks = 2 full rounds)
  gemm2<256, EPI_GELU><<<dim3(16, 32, 1), gblk, SH256, stream>>>(h2, Web, eb, 4096, 1024,
      0, 0, 0, be, nullptr, nullptr, nullptr, nullptr, 0.f);
  // contract + bias + prior -> posterior   (256 blocks)
  gemm2<128, EPI_PRIOR><<<dim3(4, 64, 1), gblk, SH128, stream>>>(eb, Wcb, out, 1024, 4096,
      0, 0, 0, bc, nullptr, nullptr, nullptr, prior, 0.f);

  loss_k<<<8192, blk, 0, stream>>>(prior, out, partial);
  loss_fin<<<1, 1024, 0, stream>>>(partial, out + 8388608);
}

// Round 5
// 458.591 us; speedup vs baseline: 1.5978x; 1.0552x over previous
//
#include <hip/hip_runtime.h>
#include <cstdint>
#include <cstddef>

typedef __bf16 bf16;
typedef __bf16 bf16x4 __attribute__((ext_vector_type(4)));
typedef __bf16 bf16x8 __attribute__((ext_vector_type(8)));
typedef float  f32x4 __attribute__((ext_vector_type(4)));

#define DEVI __device__ __forceinline__

// ---------------------------------------------------------------------------
// async global->LDS (16B per lane)
// ---------------------------------------------------------------------------
DEVI void async_ld16(void* lds, const void* g) {
  const __attribute__((address_space(1))) uint32_t* g1 =
      reinterpret_cast<const __attribute__((address_space(1))) uint32_t*>(
          reinterpret_cast<uintptr_t>(g));
  uint32_t lo = (uint32_t)reinterpret_cast<uintptr_t>(lds);
  __attribute__((address_space(3))) uint32_t* l3 =
      reinterpret_cast<__attribute__((address_space(3))) uint32_t*>(lo);
  __builtin_amdgcn_global_load_lds(g1, l3, 16, 0, 0);
}

template <int N> DEVI void wait_vmcnt() {
  asm volatile("s_waitcnt vmcnt(%0)" :: "n"(N) : "memory");
}
DEVI void blk_barrier() {
  asm volatile("" ::: "memory");
  __builtin_amdgcn_s_barrier();
  asm volatile("" ::: "memory");
}
DEVI void wait_lgkm0() {
  asm volatile("s_waitcnt lgkmcnt(0)" ::: "memory");
}

enum { EPI_BF16 = 0, EPI_QKV = 1, EPI_SCORES = 2, EPI_DYT = 3, EPI_GELU = 4, EPI_PRIOR = 5 };

// ---------------------------------------------------------------------------
// B^T GEMM, deep-pipelined: C[row,col] = sum_k A[row,k]*B[col,k]
// BN=256, BK=32, BM in {128,256}. 8 waves (2Mx4N), 512 threads.
// 4-deep LDS ring, counted vmcnt, raw s_barrier, setprio on MFMA cluster.
// NEW (R4): LDS-staged epilogue -> full-line coalesced global stores
// (16B/lane; 8-16 lanes cover one contiguous row chunk). Kills the 3.3x
// HBM write amplification of the scalar scatter epilogue.
// ---------------------------------------------------------------------------
template <int BM, int EPI>
__global__ __launch_bounds__(512, 2) void gemm2(
    const bf16* __restrict__ A, const bf16* __restrict__ Bm, void* __restrict__ Cv,
    int N, int K,
    long long bsA, long long bsB, long long bsC,
    const float* __restrict__ bias, const float* __restrict__ al,
    const float* __restrict__ wv, const float* __restrict__ bv,
    const float* __restrict__ prior, float scale)
{
  constexpr int BN = 256;
  constexpr int BK = 32;
  constexpr int ASZ = BM * BK;
  constexpr int BSZ = BN * BK;
  constexpr int SLOT = ASZ + BSZ;
  constexpr int LOADS_A = (BM * BK * 2) / (512 * 16);
  constexpr int L = LOADS_A + 2;
  constexpr int MF = BM / 32;

  extern __shared__ __align__(16) bf16 smem[];

  const int tid = threadIdx.x;

  // T1 XCD-chunked swizzle (nwg always a multiple of 8)
  const int gx = gridDim.x, gy = gridDim.y;
  const int nwg = gx * gy * gridDim.z;
  int id = (blockIdx.z * gy + blockIdx.y) * gx + blockIdx.x;
  id = (id & 7) * (nwg >> 3) + (id >> 3);
  const int bx = id % gx;
  const int t1 = id / gx;
  const int by = t1 % gy;
  const int bz = t1 / gy;

  const bf16* Ab = A  + (size_t)bz * bsA + (size_t)by * BM * K;
  const bf16* Bb = Bm + (size_t)bz * bsB + (size_t)bx * BN * K;

  const int lane = tid & 63;
  const int wid  = tid >> 6;
  const int l15 = lane & 15;
  const int lhi = lane >> 4;
  const int wr = (wid >> 2) * (BM / 2);
  const int wc = (wid & 3) * 64;

  const int sa_row = tid >> 2;
  const int sa_off = (tid & 3) * 8;

  f32x4 acc[MF][4];
  const f32x4 zero = {0.f, 0.f, 0.f, 0.f};
#pragma unroll
  for (int m = 0; m < MF; ++m)
#pragma unroll
    for (int n = 0; n < 4; ++n) acc[m][n] = zero;

  const int NT = K / BK;

  auto STAGE = [&](int t) {
    bf16* dst = smem + (size_t)(t & 3) * SLOT;
    const size_t kb = (size_t)t * BK;
#pragma unroll
    for (int i = 0; i < LOADS_A; ++i) {
      const int row = sa_row + i * 128;
      async_ld16(dst + row * BK + sa_off, Ab + (size_t)row * K + kb + sa_off);
    }
#pragma unroll
    for (int i = 0; i < 2; ++i) {
      const int row = sa_row + i * 128;
      async_ld16(dst + ASZ + row * BK + sa_off, Bb + (size_t)row * K + kb + sa_off);
    }
  };

  auto COMPUTE = [&](int t) {
    const bf16* buf = smem + (size_t)(t & 3) * SLOT;
    bf16x8 bf_[4], af_[MF];
#pragma unroll
    for (int n = 0; n < 4; ++n)
      bf_[n] = *(const bf16x8*)&buf[ASZ + (wc + n * 16 + l15) * BK + lhi * 8];
#pragma unroll
    for (int m = 0; m < MF; ++m)
      af_[m] = *(const bf16x8*)&buf[(wr + m * 16 + l15) * BK + lhi * 8];
    __builtin_amdgcn_s_setprio(1);
#pragma unroll
    for (int m = 0; m < MF; ++m)
#pragma unroll
      for (int n = 0; n < 4; ++n)
        acc[m][n] = __builtin_amdgcn_mfma_f32_16x16x32_bf16(af_[m], bf_[n], acc[m][n], 0, 0, 0);
    __builtin_amdgcn_s_setprio(0);
  };

  STAGE(0); STAGE(1); STAGE(2);

  for (int t = 0; t < NT - 3; ++t) {
    STAGE(t + 3);
    wait_vmcnt<3 * L>();
    blk_barrier();
    COMPUTE(t);
    blk_barrier();
  }
  wait_vmcnt<2 * L>(); blk_barrier(); COMPUTE(NT - 3); blk_barrier();
  wait_vmcnt<1 * L>(); blk_barrier(); COMPUTE(NT - 2); blk_barrier();
  wait_vmcnt<0>();     blk_barrier(); COMPUTE(NT - 1);

  // ---------------- epilogue: LDS-staged, coalesced ----------------
  __syncthreads();  // all waves done reading the ring; safe to reuse smem

  const int ccol_base = bx * BN + wc;   // wave's absolute col base (64 cols)
  const int wrow0 = by * BM + wr;       // wave's absolute row base

  float a2v = 0.f;
  if constexpr (EPI == EPI_DYT) a2v = al[0];

  constexpr bool F32OUT = (EPI == EPI_SCORES || EPI == EPI_PRIOR);

  if constexpr (F32OUT) {
    // wave-private [32][68] fp32 (pad 4 -> conflict-light)
    float* st = (float*)smem + wid * (32 * 68);
    const int lane4r = lane >> 4, lane16c = lane & 15;
    const int gcol = ccol_base + lane16c * 4;
#pragma unroll
    for (int mp = 0; mp < MF / 2; ++mp) {
#pragma unroll
      for (int mm = 0; mm < 2; ++mm) {
        const int m = mp * 2 + mm;
#pragma unroll
        for (int n = 0; n < 4; ++n) {
          const int col = ccol_base + n * 16 + l15;
          float bcol = 0.f;
          if constexpr (EPI == EPI_PRIOR) bcol = bias[col];
#pragma unroll
          for (int r = 0; r < 4; ++r) {
            const int lr = mm * 16 + (lhi << 2) + r;
            float v = acc[m][n][r];
            if constexpr (EPI == EPI_SCORES) {
              const int row = wrow0 + mp * 32 + lr;
              v = v * scale - fabsf((float)(row - col));
            } else {
              v += bcol;
            }
            st[lr * 68 + n * 16 + l15] = v;
          }
        }
      }
      wait_lgkm0();
#pragma unroll
      for (int k = 0; k < 8; ++k) {
        const int lr = lane4r + 4 * k;
        f32x4 v = *(const f32x4*)&st[lr * 68 + lane16c * 4];
        const int grow = wrow0 + mp * 32 + lr;
        float* C = (float*)Cv + (size_t)bz * bsC;
        if constexpr (EPI == EPI_PRIOR) {
          const float4 p = *(const float4*)&prior[(size_t)grow * 1024 + gcol];
          v[0] += p.x; v[1] += p.y; v[2] += p.z; v[3] += p.w;
        }
        *(f32x4*)&C[(size_t)grow * N + gcol] = v;
      }
      wait_lgkm0();
    }
  } else {
    // wave-private [32][72] bf16 (pad 8)
    bf16* st = (bf16*)smem + wid * (32 * 72);
    const int lane8r = lane >> 3, lane8c = lane & 7;
#pragma unroll
    for (int mp = 0; mp < MF / 2; ++mp) {
#pragma unroll
      for (int mm = 0; mm < 2; ++mm) {
        const int m = mp * 2 + mm;
#pragma unroll
        for (int n = 0; n < 4; ++n) {
          const int col = ccol_base + n * 16 + l15;
          float bcol = 0.f, wcol = 0.f, bvcol = 0.f;
          if constexpr (EPI == EPI_DYT) { bcol = bias[col]; wcol = wv[col]; bvcol = bv[col]; }
          if constexpr (EPI == EPI_GELU) bcol = bias[col];
#pragma unroll
          for (int r = 0; r < 4; ++r) {
            const int lr = mm * 16 + (lhi << 2) + r;
            const float v = acc[m][n][r];
            bf16 o;
            if constexpr (EPI == EPI_DYT) {
              o = (bf16)(tanhf(a2v * (v + bcol)) * wcol + bvcol);
            } else if constexpr (EPI == EPI_GELU) {
              const float g = v + bcol;
              o = (bf16)(0.5f * g * (1.0f + erff(g * 0.70710678118654752f)));
            } else {
              o = (bf16)v;
            }
            st[lr * 72 + n * 16 + l15] = o;
          }
        }
      }
      wait_lgkm0();
#pragma unroll
      for (int k = 0; k < 4; ++k) {
        const int lr = lane8r + 8 * k;
        const bf16x8 v = *(const bf16x8*)&st[lr * 72 + lane8c * 8];
        const int grow = wrow0 + mp * 32 + lr;
        if constexpr (EPI == EPI_QKV) {
          bf16* C = (bf16*)Cv + (size_t)(ccol_base >> 10) * bsC;
          *(bf16x8*)&C[(size_t)grow * 1024 + (ccol_base & 1023) + lane8c * 8] = v;
        } else {
          bf16* C = (bf16*)Cv + (size_t)bz * bsC;
          *(bf16x8*)&C[(size_t)grow * N + ccol_base + lane8c * 8] = v;
        }
      }
      wait_lgkm0();
    }
  }
}

// ---------------------------------------------------------------------------
// fused: xpe = x + pos_embed; prior = dyt3(xpe) (fp32); xn = dyt1(xpe) (bf16)
// ---------------------------------------------------------------------------
__global__ __launch_bounds__(256) void ew_pre(
    const float* __restrict__ x, const float* __restrict__ pe,
    const float* __restrict__ a1p, const float* __restrict__ w1, const float* __restrict__ b1,
    const float* __restrict__ a3p, const float* __restrict__ w3, const float* __restrict__ b3,
    float* __restrict__ prior, bf16* __restrict__ xn, int total4)
{
  const float a1 = a1p[0], a3 = a3p[0];
  for (int i = blockIdx.x * 256 + threadIdx.x; i < total4; i += gridDim.x * 256) {
    const int dq = i & 255;
    const float4 xv  = ((const float4*)x)[i];
    const float4 pv  = ((const float4*)pe)[dq];
    const float4 w1v = ((const float4*)w1)[dq];
    const float4 b1v = ((const float4*)b1)[dq];
    const float4 w3v = ((const float4*)w3)[dq];
    const float4 b3v = ((const float4*)b3)[dq];
    const float x0 = xv.x + pv.x, x1 = xv.y + pv.y, x2 = xv.z + pv.z, x3 = xv.w + pv.w;
    float4 prv;
    prv.x = tanhf(a3 * x0) * w3v.x + b3v.x;
    prv.y = tanhf(a3 * x1) * w3v.y + b3v.y;
    prv.z = tanhf(a3 * x2) * w3v.z + b3v.z;
    prv.w = tanhf(a3 * x3) * w3v.w + b3v.w;
    ((float4*)prior)[i] = prv;
    bf16x4 o;
    o[0] = (bf16)(tanhf(a1 * x0) * w1v.x + b1v.x);
    o[1] = (bf16)(tanhf(a1 * x1) * w1v.y + b1v.y);
    o[2] = (bf16)(tanhf(a1 * x2) * w1v.z + b1v.z);
    o[3] = (bf16)(tanhf(a1 * x3) * w1v.w + b1v.w);
    ((bf16x4*)xn)[i] = o;
  }
}

// fp32 -> bf16 weight conversion, 6 segments via blockIdx.y
__global__ __launch_bounds__(256) void conv_w(
    const float* __restrict__ s0, const float* __restrict__ s1, const float* __restrict__ s2,
    const float* __restrict__ s3, const float* __restrict__ s4, const float* __restrict__ s5,
    bf16* __restrict__ d0, bf16* __restrict__ d1, bf16* __restrict__ d2,
    bf16* __restrict__ d3, bf16* __restrict__ d4, bf16* __restrict__ d5,
    int n0, int n1, int n2, int n3, int n4, int n5)
{
  const float* s; bf16* d; int n;
  switch (blockIdx.y) {
    case 0: s = s0; d = d0; n = n0; break;
    case 1: s = s1; d = d1; n = n1; break;
    case 2: s = s2; d = d2; n = n2; break;
    case 3: s = s3; d = d3; n = n3; break;
    case 4: s = s4; d = d4; n = n4; break;
    default: s = s5; d = d5; n = n5; break;
  }
  const int nq = n >> 2;
  for (int i = blockIdx.x * 256 + threadIdx.x; i < nq; i += gridDim.x * 256) {
    const float4 v = ((const float4*)s)[i];
    bf16x4 o;
    o[0] = (bf16)v.x; o[1] = (bf16)v.y; o[2] = (bf16)v.z; o[3] = (bf16)v.w;
    ((bf16x4*)d)[i] = o;
  }
}

// V [B][T][D] -> Vt [B][D][T]
__global__ __launch_bounds__(256) void transpose_k(const bf16* __restrict__ in, bf16* __restrict__ out) {
  __shared__ bf16 tile[64][65];
  const int bx = blockIdx.x;
  const int by = blockIdx.y;
  const int bz = blockIdx.z;
  const bf16* ib = in  + (size_t)bz * 2048 * 1024;
  bf16* ob       = out + (size_t)bz * 1024 * 2048;
  const int tx = threadIdx.x & 15, ty = threadIdx.x >> 4;
#pragma unroll
  for (int i = 0; i < 4; ++i) {
    const int r = ty + i * 16;
    const bf16x4 v = *(const bf16x4*)(ib + (size_t)(by * 64 + r) * 1024 + bx * 64 + tx * 4);
    tile[r][tx * 4 + 0] = v[0]; tile[r][tx * 4 + 1] = v[1];
    tile[r][tx * 4 + 2] = v[2]; tile[r][tx * 4 + 3] = v[3];
  }
  __syncthreads();
#pragma unroll
  for (int i = 0; i < 4; ++i) {
    const int r = ty + i * 16;
    const int c = tx * 4;
    bf16x4 v;
    v[0] = tile[c + 0][r]; v[1] = tile[c + 1][r];
    v[2] = tile[c + 2][r]; v[3] = tile[c + 3][r];
    *(bf16x4*)(ob + (size_t)(bx * 64 + r) * 2048 + by * 64 + c) = v;
  }
}

// ---------------------------------------------------------------------------
// reductions
// ---------------------------------------------------------------------------
DEVI float wave_red_max(float v) {
#pragma unroll
  for (int o = 32; o > 0; o >>= 1) v = fmaxf(v, __shfl_xor(v, o));
  return v;
}
DEVI float wave_red_sum(float v) {
#pragma unroll
  for (int o = 32; o > 0; o >>= 1) v += __shfl_xor(v, o);
  return v;
}
DEVI float block_red_max(float v, float* sm) {
  v = wave_red_max(v);
  if ((threadIdx.x & 63) == 0) sm[threadIdx.x >> 6] = v;
  __syncthreads();
  v = fmaxf(fmaxf(sm[0], sm[1]), fmaxf(sm[2], sm[3]));
  __syncthreads();
  return v;
}
DEVI float block_red_sum(float v, float* sm) {
  v = wave_red_sum(v);
  if ((threadIdx.x & 63) == 0) sm[threadIdx.x >> 6] = v;
  __syncthreads();
  v = sm[0] + sm[1] + sm[2] + sm[3];
  __syncthreads();
  return v;
}

// row softmax over 2048 scores (fp32 in) -> bf16 probs
__global__ __launch_bounds__(256) void softmax_k(const float* __restrict__ scores, bf16* __restrict__ probs) {
  __shared__ float sm[4];
  const size_t row = blockIdx.x;
  const float* s = scores + row * 2048;
  bf16* p = probs + row * 2048;
  const int t = threadIdx.x;
  const float4 v0 = *(const float4*)&s[t * 4];
  const float4 v1 = *(const float4*)&s[1024 + t * 4];
  float mx = fmaxf(fmaxf(fmaxf(v0.x, v0.y), fmaxf(v0.z, v0.w)),
                   fmaxf(fmaxf(v1.x, v1.y), fmaxf(v1.z, v1.w)));
  mx = block_red_max(mx, sm);
  const float e0 = expf(v0.x - mx), e1 = expf(v0.y - mx), e2 = expf(v0.z - mx), e3 = expf(v0.w - mx);
  const float e4 = expf(v1.x - mx), e5 = expf(v1.y - mx), e6 = expf(v1.z - mx), e7 = expf(v1.w - mx);
  float ssum = e0 + e1 + e2 + e3 + e4 + e5 + e6 + e7;
  ssum = block_red_sum(ssum, sm);
  const float inv = 1.0f / ssum;
  bf16x4 o0, o1;
  o0[0] = (bf16)(e0 * inv); o0[1] = (bf16)(e1 * inv); o0[2] = (bf16)(e2 * inv); o0[3] = (bf16)(e3 * inv);
  o1[0] = (bf16)(e4 * inv); o1[1] = (bf16)(e5 * inv); o1[2] = (bf16)(e6 * inv); o1[3] = (bf16)(e7 * inv);
  *(bf16x4*)&p[t * 4] = o0;
  *(bf16x4*)&p[1024 + t * 4] = o1;
}

// per-row JS pieces -> per-row partials
__global__ __launch_bounds__(256) void loss_k(const float* __restrict__ prior,
                                              const float* __restrict__ post,
                                              float* __restrict__ partial) {
  __shared__ float sm[4];
  const size_t row = blockIdx.x;
  const int t = threadIdx.x;
  const float4 pr = *(const float4*)&prior[row * 1024 + t * 4];
  const float4 po = *(const float4*)&post[row * 1024 + t * 4];
  float4 mm;
  mm.x = 0.5f * (pr.x + po.x); mm.y = 0.5f * (pr.y + po.y);
  mm.z = 0.5f * (pr.z + po.z); mm.w = 0.5f * (pr.w + po.w);
  const float mxp = block_red_max(fmaxf(fmaxf(pr.x, pr.y), fmaxf(pr.z, pr.w)), sm);
  const float mxo = block_red_max(fmaxf(fmaxf(po.x, po.y), fmaxf(po.z, po.w)), sm);
  const float mxm = block_red_max(fmaxf(fmaxf(mm.x, mm.y), fmaxf(mm.z, mm.w)), sm);
  float sp = expf(pr.x - mxp) + expf(pr.y - mxp) + expf(pr.z - mxp) + expf(pr.w - mxp);
  sp = block_red_sum(sp, sm);
  float so = expf(po.x - mxo) + expf(po.y - mxo) + expf(po.z - mxo) + expf(po.w - mxo);
  so = block_red_sum(so, sm);
  const float em0 = expf(mm.x - mxm), em1 = expf(mm.y - mxm), em2 = expf(mm.z - mxm), em3 = expf(mm.w - mxm);
  float smm = block_red_sum(em0 + em1 + em2 + em3, sm);
  const float invm = 1.0f / smm;
  float s1 = em0 * invm * (mm.x - pr.x) + em1 * invm * (mm.y - pr.y) +
             em2 * invm * (mm.z - pr.z) + em3 * invm * (mm.w - pr.w);
  float s2 = em0 * invm * (mm.x - po.x) + em1 * invm * (mm.y - po.y) +
             em2 * invm * (mm.z - po.z) + em3 * invm * (mm.w - po.w);
  s1 = block_red_sum(s1, sm);
  s2 = block_red_sum(s2, sm);
  if (t == 0) {
    const float logZp = mxp + logf(sp);
    const float logZo = mxo + logf(so);
    const float logZm = mxm + logf(smm);
    partial[row]        = s1 + (logZp - logZm);
    partial[8192 + row] = s2 + (logZo - logZm);
  }
}

__global__ __launch_bounds__(1024) void loss_fin(const float* __restrict__ partial,
                                                 float* __restrict__ out) {
  __shared__ float sm[32];
  const int t = threadIdx.x;
  float a = 0.f, b = 0.f;
  for (int i = t; i < 8192; i += 1024) {
    a += partial[i];
    b += partial[8192 + i];
  }
  float v = a + b;
#pragma unroll
  for (int o = 32; o > 0; o >>= 1) v += __shfl_xor(v, o);
  if ((t & 63) == 0) sm[t >> 6] = v;
  __syncthreads();
  if (t == 0) {
    float s = 0.f;
#pragma unroll
    for (int w = 0; w < 16; ++w) s += sm[w];
    out[0] = 0.125f * s;
  }
}

// ---------------------------------------------------------------------------
extern "C" void kernel_launch(void* const* d_in, const int* in_sizes, int n_in,
                              void* d_out, int out_size, void* d_ws, size_t ws_size,
                              hipStream_t stream) {
  const float* x  = (const float*)d_in[0];
  const float* pe = (const float*)d_in[1];
  const float* a1 = (const float*)d_in[2];
  const float* w1 = (const float*)d_in[3];
  const float* b1 = (const float*)d_in[4];
  const float* a2 = (const float*)d_in[5];
  const float* w2 = (const float*)d_in[6];
  const float* b2 = (const float*)d_in[7];
  const float* a3 = (const float*)d_in[8];
  const float* w3 = (const float*)d_in[9];
  const float* b3 = (const float*)d_in[10];
  const float* Wq = (const float*)d_in[11];
  const float* Wk = (const float*)d_in[12];
  const float* Wv = (const float*)d_in[13];
  const float* Wp = (const float*)d_in[14];
  const float* bp = (const float*)d_in[15];
  const float* We = (const float*)d_in[16];
  const float* be = (const float*)d_in[17];
  const float* Wc = (const float*)d_in[18];
  const float* bc = (const float*)d_in[19];
  float* out = (float*)d_out;

  char* ws = (char*)d_ws;
  float* prior  = (float*)(ws + 0);
  bf16*  xn     = (bf16*)(ws + 33554432ull);
  bf16*  Qb     = (bf16*)(ws + 50331648ull);
  bf16*  Kb     = (bf16*)(ws + 67108864ull);
  bf16*  Vb     = (bf16*)(ws + 83886080ull);
  bf16*  Vt     = (bf16*)(ws + 100663296ull);
  float* scores = (float*)(ws + 117440512ull);
  bf16*  Wqb    = (bf16*)(ws + 184549376ull);   // Wq/Wk/Wv contiguous
  bf16*  Wkb    = (bf16*)(ws + 186646528ull);
  bf16*  Wvb    = (bf16*)(ws + 188743680ull);
  bf16*  Wpb    = (bf16*)(ws + 190840832ull);
  bf16*  Web    = (bf16*)(ws + 192937984ull);
  bf16*  Wcb    = (bf16*)(ws + 201326592ull);
  bf16*  attno  = xn;
  bf16*  h2     = Qb;
  bf16*  eb     = (bf16*)scores;
  float* partial = (float*)(ws + 117440512ull);
  bf16*  probs  = (bf16*)d_out;

  static bool attr_done = false;
  if (!attr_done) {
    hipFuncSetAttribute((const void*)gemm2<128, EPI_QKV>,   hipFuncAttributeMaxDynamicSharedMemorySize, 131072);
    hipFuncSetAttribute((const void*)gemm2<256, EPI_SCORES>,hipFuncAttributeMaxDynamicSharedMemorySize, 131072);
    hipFuncSetAttribute((const void*)gemm2<128, EPI_BF16>,  hipFuncAttributeMaxDynamicSharedMemorySize, 131072);
    hipFuncSetAttribute((const void*)gemm2<128, EPI_DYT>,   hipFuncAttributeMaxDynamicSharedMemorySize, 131072);
    hipFuncSetAttribute((const void*)gemm2<256, EPI_GELU>,  hipFuncAttributeMaxDynamicSharedMemorySize, 131072);
    hipFuncSetAttribute((const void*)gemm2<128, EPI_PRIOR>, hipFuncAttributeMaxDynamicSharedMemorySize, 131072);
    attr_done = true;
  }

  dim3 blk(256);
  dim3 gblk(512);
  constexpr unsigned SH128 = 98304;    // ring: (128*32 + 256*32)*2B * 4
  constexpr unsigned SH256 = 131072;   // ring: (256*32 + 256*32)*2B * 4

  conv_w<<<dim3(1024, 6), blk, 0, stream>>>(Wq, Wk, Wv, Wp, We, Wc,
                                            Wqb, Wkb, Wvb, Wpb, Web, Wcb,
                                            1048576, 1048576, 1048576, 1048576, 4194304, 4194304);
  ew_pre<<<2048, blk, 0, stream>>>(x, pe, a1, w1, b1, a3, w3, b3, prior, xn, 2097152);

  // fused QKV: [8192,3072] = xn @ [Wq;Wk;Wv]^T
  gemm2<128, EPI_QKV><<<dim3(12, 64, 1), gblk, SH128, stream>>>(xn, Wqb, Qb, 3072, 1024,
      0, 0, 8388608ll, nullptr, nullptr, nullptr, nullptr, nullptr, 0.f);
  transpose_k<<<dim3(16, 32, 4), blk, 0, stream>>>(Vb, Vt);

  // scores[b,t,s] = (Q·K)/32 - |t-s|
  gemm2<256, EPI_SCORES><<<dim3(8, 8, 4), gblk, SH256, stream>>>(Qb, Kb, scores, 2048, 1024,
      2097152ll, 2097152ll, 4194304ll, nullptr, nullptr, nullptr, nullptr, nullptr, 0.03125f);
  softmax_k<<<8192, blk, 0, stream>>>(scores, probs);

  // out[b,t,d] = probs @ Vt
  gemm2<128, EPI_BF16><<<dim3(4, 16, 4), gblk, SH128, stream>>>(probs, Vt, attno, 1024, 2048,
      4194304ll, 2097152ll, 2097152ll, nullptr, nullptr, nullptr, nullptr, nullptr, 0.f);

  // proj + dyt2
  gemm2<128, EPI_DYT><<<dim3(4, 64, 1), gblk, SH128, stream>>>(attno, Wpb, h2, 1024, 1024,
      0, 0, 0, bp, a2, w2, b2, nullptr, 0.f);
  // expand + exact gelu
  gemm2<256, EPI_GELU><<<dim3(16, 32, 1), gblk, SH256, stream>>>(h2, Web, eb, 4096, 1024,
      0, 0, 0, be, nullptr, nullptr, nullptr, nullptr, 0.f);
  // contract + bias + prior -> posterior
  gemm2<128, EPI_PRIOR><<<dim3(4, 64, 1), gblk, SH128, stream>>>(eb, Wcb, out, 1024, 4096,
      0, 0, 0, bc, nullptr, nullptr, nullptr, prior, 0.f);

  loss_k<<<8192, blk, 0, stream>>>(prior, out, partial);
  loss_fin<<<1, 1024, 0, stream>>>(partial, out + 8388608);
}

// Round 6
// 416.571 us; speedup vs baseline: 1.7590x; 1.1009x over previous
//
#include <hip/hip_runtime.h>
#include <cstdint>
#include <cstddef>

typedef __bf16 bf16;
typedef __bf16 bf16x4 __attribute__((ext_vector_type(4)));
typedef __bf16 bf16x8 __attribute__((ext_vector_type(8)));
typedef float  f32x4 __attribute__((ext_vector_type(4)));

#define DEVI __device__ __forceinline__

// ---------------------------------------------------------------------------
// async global->LDS (16B per lane)
// ---------------------------------------------------------------------------
DEVI void async_ld16(void* lds, const void* g) {
  const __attribute__((address_space(1))) uint32_t* g1 =
      reinterpret_cast<const __attribute__((address_space(1))) uint32_t*>(
          reinterpret_cast<uintptr_t>(g));
  uint32_t lo = (uint32_t)reinterpret_cast<uintptr_t>(lds);
  __attribute__((address_space(3))) uint32_t* l3 =
      reinterpret_cast<__attribute__((address_space(3))) uint32_t*>(lo);
  __builtin_amdgcn_global_load_lds(g1, l3, 16, 0, 0);
}

template <int N> DEVI void wait_vmcnt() {
  asm volatile("s_waitcnt vmcnt(%0)" :: "n"(N) : "memory");
}
DEVI void blk_barrier() {
  asm volatile("" ::: "memory");
  __builtin_amdgcn_s_barrier();
  asm volatile("" ::: "memory");
}
DEVI void wait_lgkm0() {
  asm volatile("s_waitcnt lgkmcnt(0)" ::: "memory");
}

enum { EPI_BF16 = 0, EPI_QKV = 1, EPI_SCORES = 2, EPI_DYT = 3, EPI_GELU = 4, EPI_PRIOR = 5 };

// ---------------------------------------------------------------------------
// B^T GEMM: C[row,col] = sum_k A[row,k]*B[col,k]
// BM=128, BN=256, BK=32. 8 waves (2Mx4N), 512 threads.
// R5: ring-3 LDS (72KB) + __launch_bounds__(512,4) -> 2 blocks/CU so a
// second block hides the per-tile barrier skew (was 1 block/CU = 2ph ceiling).
// K-octet XOR swizzle (slot ^= (row>>1)&3) applied on BOTH the pre-swizzled
// global source and the ds_read -> all 8 bank-groups used, 2-way max (free).
// Counted vmcnt (never 0 in main loop), raw s_barrier, setprio on MFMA.
// LDS-staged coalesced epilogue (R4).
// ---------------------------------------------------------------------------
template <int EPI>
__global__ __launch_bounds__(512, 4) void gemm2(
    const bf16* __restrict__ A, const bf16* __restrict__ Bm, void* __restrict__ Cv,
    int N, int K,
    long long bsA, long long bsB, long long bsC,
    const float* __restrict__ bias, const float* __restrict__ al,
    const float* __restrict__ wv, const float* __restrict__ bv,
    const float* __restrict__ prior, float scale)
{
  constexpr int BM = 128;
  constexpr int BN = 256;
  constexpr int BK = 32;
  constexpr int ASZ = BM * BK;          // 4096 elems
  constexpr int SLOT = ASZ + BN * BK;   // 12288 elems = 24KB
  constexpr int L = 3;                  // loads per thread per tile (1 A + 2 B)
  constexpr int MF = 4;                 // m-frags per wave (128/2/16)

  extern __shared__ __align__(16) bf16 smem[];  // 3 * SLOT

  const int tid = threadIdx.x;

  // T1 XCD-chunked swizzle (nwg always a multiple of 8)
  const int gx = gridDim.x, gy = gridDim.y;
  const int nwg = gx * gy * gridDim.z;
  int id = (blockIdx.z * gy + blockIdx.y) * gx + blockIdx.x;
  id = (id & 7) * (nwg >> 3) + (id >> 3);
  const int bx = id % gx;
  const int t1 = id / gx;
  const int by = t1 % gy;
  const int bz = t1 / gy;

  const bf16* Ab = A  + (size_t)bz * bsA + (size_t)by * BM * K;
  const bf16* Bb = Bm + (size_t)bz * bsB + (size_t)bx * BN * K;

  const int lane = tid & 63;
  const int wid  = tid >> 6;
  const int l15 = lane & 15;
  const int lhi = lane >> 4;
  const int wr = (wid >> 2) * 64;
  const int wc = (wid & 3) * 64;

  // staging: thread -> (row = tid>>2, slot p = tid&3); LDS dst linear in lane.
  // source k-octet = p ^ ((row>>1)&3)  (inverse swizzle on global address)
  const int srow = tid >> 2;
  const int sp   = tid & 3;
  const int soct = (sp ^ ((srow >> 1) & 3)) << 3;
  const bf16* aSrc  = Ab + (size_t)srow * K + soct;
  const bf16* bSrc0 = Bb + (size_t)srow * K + soct;
  const bf16* bSrc1 = Bb + (size_t)(srow + 128) * K + soct;
  const int dstA = tid * 8;             // elems within slot
  const int dstB0 = ASZ + tid * 8;
  const int dstB1 = ASZ + 4096 + tid * 8;

  // ds_read swizzled k-offset: lhi ^ ((l15>>1)&3)  (independent of m,n)
  const int koff = ((lhi ^ ((l15 >> 1) & 3)) << 3);

  f32x4 acc[MF][4];
  const f32x4 zero = {0.f, 0.f, 0.f, 0.f};
#pragma unroll
  for (int m = 0; m < MF; ++m)
#pragma unroll
    for (int n = 0; n < 4; ++n) acc[m][n] = zero;

  const int NT = K / BK;

  auto STAGE = [&](int t) {
    bf16* dst = smem + (size_t)(t % 3) * SLOT;
    const size_t kb = (size_t)t * BK;
    async_ld16(dst + dstA,  aSrc  + kb);
    async_ld16(dst + dstB0, bSrc0 + kb);
    async_ld16(dst + dstB1, bSrc1 + kb);
  };

  auto COMPUTE = [&](int t) {
    const bf16* buf = smem + (size_t)(t % 3) * SLOT;
    bf16x8 bf_[4];
#pragma unroll
    for (int n = 0; n < 4; ++n)
      bf_[n] = *(const bf16x8*)&buf[ASZ + (wc + n * 16 + l15) * BK + koff];
    __builtin_amdgcn_s_setprio(1);
#pragma unroll
    for (int m = 0; m < MF; ++m) {
      const bf16x8 af_ = *(const bf16x8*)&buf[(wr + m * 16 + l15) * BK + koff];
#pragma unroll
      for (int n = 0; n < 4; ++n)
        acc[m][n] = __builtin_amdgcn_mfma_f32_16x16x32_bf16(af_, bf_[n], acc[m][n], 0, 0, 0);
    }
    __builtin_amdgcn_s_setprio(0);
  };

  STAGE(0); STAGE(1);

  for (int t = 0; t < NT - 2; ++t) {
    STAGE(t + 2);
    wait_vmcnt<2 * L>();
    blk_barrier();
    COMPUTE(t);
    blk_barrier();
  }
  wait_vmcnt<L>(); blk_barrier(); COMPUTE(NT - 2); blk_barrier();
  wait_vmcnt<0>(); blk_barrier(); COMPUTE(NT - 1);

  // ---------------- epilogue: LDS-staged, coalesced ----------------
  __syncthreads();

  const int ccol_base = bx * BN + wc;
  const int wrow0 = by * BM + wr;

  float a2v = 0.f;
  if constexpr (EPI == EPI_DYT) a2v = al[0];

  constexpr bool F32OUT = (EPI == EPI_SCORES || EPI == EPI_PRIOR);

  if constexpr (F32OUT) {
    float* st = (float*)smem + wid * (32 * 68);
    const int lane4r = lane >> 4, lane16c = lane & 15;
    const int gcol = ccol_base + lane16c * 4;
#pragma unroll
    for (int mp = 0; mp < MF / 2; ++mp) {
#pragma unroll
      for (int mm = 0; mm < 2; ++mm) {
        const int m = mp * 2 + mm;
#pragma unroll
        for (int n = 0; n < 4; ++n) {
          const int col = ccol_base + n * 16 + l15;
          float bcol = 0.f;
          if constexpr (EPI == EPI_PRIOR) bcol = bias[col];
#pragma unroll
          for (int r = 0; r < 4; ++r) {
            const int lr = mm * 16 + (lhi << 2) + r;
            float v = acc[m][n][r];
            if constexpr (EPI == EPI_SCORES) {
              const int row = wrow0 + mp * 32 + lr;
              v = v * scale - fabsf((float)(row - col));
            } else {
              v += bcol;
            }
            st[lr * 68 + n * 16 + l15] = v;
          }
        }
      }
      wait_lgkm0();
#pragma unroll
      for (int k = 0; k < 8; ++k) {
        const int lr = lane4r + 4 * k;
        f32x4 v = *(const f32x4*)&st[lr * 68 + lane16c * 4];
        const int grow = wrow0 + mp * 32 + lr;
        float* C = (float*)Cv + (size_t)bz * bsC;
        if constexpr (EPI == EPI_PRIOR) {
          const float4 p = *(const float4*)&prior[(size_t)grow * 1024 + gcol];
          v[0] += p.x; v[1] += p.y; v[2] += p.z; v[3] += p.w;
        }
        *(f32x4*)&C[(size_t)grow * N + gcol] = v;
      }
      wait_lgkm0();
    }
  } else {
    bf16* st = (bf16*)smem + wid * (32 * 72);
    const int lane8r = lane >> 3, lane8c = lane & 7;
#pragma unroll
    for (int mp = 0; mp < MF / 2; ++mp) {
#pragma unroll
      for (int mm = 0; mm < 2; ++mm) {
        const int m = mp * 2 + mm;
#pragma unroll
        for (int n = 0; n < 4; ++n) {
          const int col = ccol_base + n * 16 + l15;
          float bcol = 0.f, wcol = 0.f, bvcol = 0.f;
          if constexpr (EPI == EPI_DYT) { bcol = bias[col]; wcol = wv[col]; bvcol = bv[col]; }
          if constexpr (EPI == EPI_GELU) bcol = bias[col];
#pragma unroll
          for (int r = 0; r < 4; ++r) {
            const int lr = mm * 16 + (lhi << 2) + r;
            const float v = acc[m][n][r];
            bf16 o;
            if constexpr (EPI == EPI_DYT) {
              o = (bf16)(tanhf(a2v * (v + bcol)) * wcol + bvcol);
            } else if constexpr (EPI == EPI_GELU) {
              const float g = v + bcol;
              o = (bf16)(0.5f * g * (1.0f + erff(g * 0.70710678118654752f)));
            } else {
              o = (bf16)v;
            }
            st[lr * 72 + n * 16 + l15] = o;
          }
        }
      }
      wait_lgkm0();
#pragma unroll
      for (int k = 0; k < 4; ++k) {
        const int lr = lane8r + 8 * k;
        const bf16x8 v = *(const bf16x8*)&st[lr * 72 + lane8c * 8];
        const int grow = wrow0 + mp * 32 + lr;
        if constexpr (EPI == EPI_QKV) {
          bf16* C = (bf16*)Cv + (size_t)(ccol_base >> 10) * bsC;
          *(bf16x8*)&C[(size_t)grow * 1024 + (ccol_base & 1023) + lane8c * 8] = v;
        } else {
          bf16* C = (bf16*)Cv + (size_t)bz * bsC;
          *(bf16x8*)&C[(size_t)grow * N + ccol_base + lane8c * 8] = v;
        }
      }
      wait_lgkm0();
    }
  }
}

// ---------------------------------------------------------------------------
// fused: xpe = x + pos_embed; prior = dyt3(xpe) (fp32); xn = dyt1(xpe) (bf16)
// ---------------------------------------------------------------------------
__global__ __launch_bounds__(256) void ew_pre(
    const float* __restrict__ x, const float* __restrict__ pe,
    const float* __restrict__ a1p, const float* __restrict__ w1, const float* __restrict__ b1,
    const float* __restrict__ a3p, const float* __restrict__ w3, const float* __restrict__ b3,
    float* __restrict__ prior, bf16* __restrict__ xn, int total4)
{
  const float a1 = a1p[0], a3 = a3p[0];
  for (int i = blockIdx.x * 256 + threadIdx.x; i < total4; i += gridDim.x * 256) {
    const int dq = i & 255;
    const float4 xv  = ((const float4*)x)[i];
    const float4 pv  = ((const float4*)pe)[dq];
    const float4 w1v = ((const float4*)w1)[dq];
    const float4 b1v = ((const float4*)b1)[dq];
    const float4 w3v = ((const float4*)w3)[dq];
    const float4 b3v = ((const float4*)b3)[dq];
    const float x0 = xv.x + pv.x, x1 = xv.y + pv.y, x2 = xv.z + pv.z, x3 = xv.w + pv.w;
    float4 prv;
    prv.x = tanhf(a3 * x0) * w3v.x + b3v.x;
    prv.y = tanhf(a3 * x1) * w3v.y + b3v.y;
    prv.z = tanhf(a3 * x2) * w3v.z + b3v.z;
    prv.w = tanhf(a3 * x3) * w3v.w + b3v.w;
    ((float4*)prior)[i] = prv;
    bf16x4 o;
    o[0] = (bf16)(tanhf(a1 * x0) * w1v.x + b1v.x);
    o[1] = (bf16)(tanhf(a1 * x1) * w1v.y + b1v.y);
    o[2] = (bf16)(tanhf(a1 * x2) * w1v.z + b1v.z);
    o[3] = (bf16)(tanhf(a1 * x3) * w1v.w + b1v.w);
    ((bf16x4*)xn)[i] = o;
  }
}

// fp32 -> bf16 weight conversion, 6 segments via blockIdx.y
__global__ __launch_bounds__(256) void conv_w(
    const float* __restrict__ s0, const float* __restrict__ s1, const float* __restrict__ s2,
    const float* __restrict__ s3, const float* __restrict__ s4, const float* __restrict__ s5,
    bf16* __restrict__ d0, bf16* __restrict__ d1, bf16* __restrict__ d2,
    bf16* __restrict__ d3, bf16* __restrict__ d4, bf16* __restrict__ d5,
    int n0, int n1, int n2, int n3, int n4, int n5)
{
  const float* s; bf16* d; int n;
  switch (blockIdx.y) {
    case 0: s = s0; d = d0; n = n0; break;
    case 1: s = s1; d = d1; n = n1; break;
    case 2: s = s2; d = d2; n = n2; break;
    case 3: s = s3; d = d3; n = n3; break;
    case 4: s = s4; d = d4; n = n4; break;
    default: s = s5; d = d5; n = n5; break;
  }
  const int nq = n >> 2;
  for (int i = blockIdx.x * 256 + threadIdx.x; i < nq; i += gridDim.x * 256) {
    const float4 v = ((const float4*)s)[i];
    bf16x4 o;
    o[0] = (bf16)v.x; o[1] = (bf16)v.y; o[2] = (bf16)v.z; o[3] = (bf16)v.w;
    ((bf16x4*)d)[i] = o;
  }
}

// V [B][T][D] -> Vt [B][D][T]
__global__ __launch_bounds__(256) void transpose_k(const bf16* __restrict__ in, bf16* __restrict__ out) {
  __shared__ bf16 tile[64][65];
  const int bx = blockIdx.x;
  const int by = blockIdx.y;
  const int bz = blockIdx.z;
  const bf16* ib = in  + (size_t)bz * 2048 * 1024;
  bf16* ob       = out + (size_t)bz * 1024 * 2048;
  const int tx = threadIdx.x & 15, ty = threadIdx.x >> 4;
#pragma unroll
  for (int i = 0; i < 4; ++i) {
    const int r = ty + i * 16;
    const bf16x4 v = *(const bf16x4*)(ib + (size_t)(by * 64 + r) * 1024 + bx * 64 + tx * 4);
    tile[r][tx * 4 + 0] = v[0]; tile[r][tx * 4 + 1] = v[1];
    tile[r][tx * 4 + 2] = v[2]; tile[r][tx * 4 + 3] = v[3];
  }
  __syncthreads();
#pragma unroll
  for (int i = 0; i < 4; ++i) {
    const int r = ty + i * 16;
    const int c = tx * 4;
    bf16x4 v;
    v[0] = tile[c + 0][r]; v[1] = tile[c + 1][r];
    v[2] = tile[c + 2][r]; v[3] = tile[c + 3][r];
    *(bf16x4*)(ob + (size_t)(bx * 64 + r) * 2048 + by * 64 + c) = v;
  }
}

// ---------------------------------------------------------------------------
// reductions
// ---------------------------------------------------------------------------
DEVI float wave_red_max(float v) {
#pragma unroll
  for (int o = 32; o > 0; o >>= 1) v = fmaxf(v, __shfl_xor(v, o));
  return v;
}
DEVI float wave_red_sum(float v) {
#pragma unroll
  for (int o = 32; o > 0; o >>= 1) v += __shfl_xor(v, o);
  return v;
}
DEVI float block_red_max(float v, float* sm) {
  v = wave_red_max(v);
  if ((threadIdx.x & 63) == 0) sm[threadIdx.x >> 6] = v;
  __syncthreads();
  v = fmaxf(fmaxf(sm[0], sm[1]), fmaxf(sm[2], sm[3]));
  __syncthreads();
  return v;
}
DEVI float block_red_sum(float v, float* sm) {
  v = wave_red_sum(v);
  if ((threadIdx.x & 63) == 0) sm[threadIdx.x >> 6] = v;
  __syncthreads();
  v = sm[0] + sm[1] + sm[2] + sm[3];
  __syncthreads();
  return v;
}

// row softmax over 2048 scores (fp32 in) -> bf16 probs
__global__ __launch_bounds__(256) void softmax_k(const float* __restrict__ scores, bf16* __restrict__ probs) {
  __shared__ float sm[4];
  const size_t row = blockIdx.x;
  const float* s = scores + row * 2048;
  bf16* p = probs + row * 2048;
  const int t = threadIdx.x;
  const float4 v0 = *(const float4*)&s[t * 4];
  const float4 v1 = *(const float4*)&s[1024 + t * 4];
  float mx = fmaxf(fmaxf(fmaxf(v0.x, v0.y), fmaxf(v0.z, v0.w)),
                   fmaxf(fmaxf(v1.x, v1.y), fmaxf(v1.z, v1.w)));
  mx = block_red_max(mx, sm);
  const float e0 = expf(v0.x - mx), e1 = expf(v0.y - mx), e2 = expf(v0.z - mx), e3 = expf(v0.w - mx);
  const float e4 = expf(v1.x - mx), e5 = expf(v1.y - mx), e6 = expf(v1.z - mx), e7 = expf(v1.w - mx);
  float ssum = e0 + e1 + e2 + e3 + e4 + e5 + e6 + e7;
  ssum = block_red_sum(ssum, sm);
  const float inv = 1.0f / ssum;
  bf16x4 o0, o1;
  o0[0] = (bf16)(e0 * inv); o0[1] = (bf16)(e1 * inv); o0[2] = (bf16)(e2 * inv); o0[3] = (bf16)(e3 * inv);
  o1[0] = (bf16)(e4 * inv); o1[1] = (bf16)(e5 * inv); o1[2] = (bf16)(e6 * inv); o1[3] = (bf16)(e7 * inv);
  *(bf16x4*)&p[t * 4] = o0;
  *(bf16x4*)&p[1024 + t * 4] = o1;
}

// per-row JS pieces -> per-row partials
__global__ __launch_bounds__(256) void loss_k(const float* __restrict__ prior,
                                              const float* __restrict__ post,
                                              float* __restrict__ partial) {
  __shared__ float sm[4];
  const size_t row = blockIdx.x;
  const int t = threadIdx.x;
  const float4 pr = *(const float4*)&prior[row * 1024 + t * 4];
  const float4 po = *(const float4*)&post[row * 1024 + t * 4];
  float4 mm;
  mm.x = 0.5f * (pr.x + po.x); mm.y = 0.5f * (pr.y + po.y);
  mm.z = 0.5f * (pr.z + po.z); mm.w = 0.5f * (pr.w + po.w);
  const float mxp = block_red_max(fmaxf(fmaxf(pr.x, pr.y), fmaxf(pr.z, pr.w)), sm);
  const float mxo = block_red_max(fmaxf(fmaxf(po.x, po.y), fmaxf(po.z, po.w)), sm);
  const float mxm = block_red_max(fmaxf(fmaxf(mm.x, mm.y), fmaxf(mm.z, mm.w)), sm);
  float sp = expf(pr.x - mxp) + expf(pr.y - mxp) + expf(pr.z - mxp) + expf(pr.w - mxp);
  sp = block_red_sum(sp, sm);
  float so = expf(po.x - mxo) + expf(po.y - mxo) + expf(po.z - mxo) + expf(po.w - mxo);
  so = block_red_sum(so, sm);
  const float em0 = expf(mm.x - mxm), em1 = expf(mm.y - mxm), em2 = expf(mm.z - mxm), em3 = expf(mm.w - mxm);
  float smm = block_red_sum(em0 + em1 + em2 + em3, sm);
  const float invm = 1.0f / smm;
  float s1 = em0 * invm * (mm.x - pr.x) + em1 * invm * (mm.y - pr.y) +
             em2 * invm * (mm.z - pr.z) + em3 * invm * (mm.w - pr.w);
  float s2 = em0 * invm * (mm.x - po.x) + em1 * invm * (mm.y - po.y) +
             em2 * invm * (mm.z - po.z) + em3 * invm * (mm.w - po.w);
  s1 = block_red_sum(s1, sm);
  s2 = block_red_sum(s2, sm);
  if (t == 0) {
    const float logZp = mxp + logf(sp);
    const float logZo = mxo + logf(so);
    const float logZm = mxm + logf(smm);
    partial[row]        = s1 + (logZp - logZm);
    partial[8192 + row] = s2 + (logZo - logZm);
  }
}

__global__ __launch_bounds__(1024) void loss_fin(const float* __restrict__ partial,
                                                 float* __restrict__ out) {
  __shared__ float sm[32];
  const int t = threadIdx.x;
  float a = 0.f, b = 0.f;
  for (int i = t; i < 8192; i += 1024) {
    a += partial[i];
    b += partial[8192 + i];
  }
  float v = a + b;
#pragma unroll
  for (int o = 32; o > 0; o >>= 1) v += __shfl_xor(v, o);
  if ((t & 63) == 0) sm[t >> 6] = v;
  __syncthreads();
  if (t == 0) {
    float s = 0.f;
#pragma unroll
    for (int w = 0; w < 16; ++w) s += sm[w];
    out[0] = 0.125f * s;
  }
}

// ---------------------------------------------------------------------------
extern "C" void kernel_launch(void* const* d_in, const int* in_sizes, int n_in,
                              void* d_out, int out_size, void* d_ws, size_t ws_size,
                              hipStream_t stream) {
  const float* x  = (const float*)d_in[0];
  const float* pe = (const float*)d_in[1];
  const float* a1 = (const float*)d_in[2];
  const float* w1 = (const float*)d_in[3];
  const float* b1 = (const float*)d_in[4];
  const float* a2 = (const float*)d_in[5];
  const float* w2 = (const float*)d_in[6];
  const float* b2 = (const float*)d_in[7];
  const float* a3 = (const float*)d_in[8];
  const float* w3 = (const float*)d_in[9];
  const float* b3 = (const float*)d_in[10];
  const float* Wq = (const float*)d_in[11];
  const float* Wk = (const float*)d_in[12];
  const float* Wv = (const float*)d_in[13];
  const float* Wp = (const float*)d_in[14];
  const float* bp = (const float*)d_in[15];
  const float* We = (const float*)d_in[16];
  const float* be = (const float*)d_in[17];
  const float* Wc = (const float*)d_in[18];
  const float* bc = (const float*)d_in[19];
  float* out = (float*)d_out;

  char* ws = (char*)d_ws;
  float* prior  = (float*)(ws + 0);
  bf16*  xn     = (bf16*)(ws + 33554432ull);
  bf16*  Qb     = (bf16*)(ws + 50331648ull);
  bf16*  Kb     = (bf16*)(ws + 67108864ull);
  bf16*  Vb     = (bf16*)(ws + 83886080ull);
  bf16*  Vt     = (bf16*)(ws + 100663296ull);
  float* scores = (float*)(ws + 117440512ull);
  bf16*  Wqb    = (bf16*)(ws + 184549376ull);   // Wq/Wk/Wv contiguous
  bf16*  Wkb    = (bf16*)(ws + 186646528ull);
  bf16*  Wvb    = (bf16*)(ws + 188743680ull);
  bf16*  Wpb    = (bf16*)(ws + 190840832ull);
  bf16*  Web    = (bf16*)(ws + 192937984ull);
  bf16*  Wcb    = (bf16*)(ws + 201326592ull);
  bf16*  attno  = xn;
  bf16*  h2     = Qb;
  bf16*  eb     = (bf16*)scores;
  float* partial = (float*)(ws + 117440512ull);
  bf16*  probs  = (bf16*)d_out;

  static bool attr_done = false;
  if (!attr_done) {
    hipFuncSetAttribute((const void*)gemm2<EPI_QKV>,   hipFuncAttributeMaxDynamicSharedMemorySize, 73728);
    hipFuncSetAttribute((const void*)gemm2<EPI_SCORES>,hipFuncAttributeMaxDynamicSharedMemorySize, 73728);
    hipFuncSetAttribute((const void*)gemm2<EPI_BF16>,  hipFuncAttributeMaxDynamicSharedMemorySize, 73728);
    hipFuncSetAttribute((const void*)gemm2<EPI_DYT>,   hipFuncAttributeMaxDynamicSharedMemorySize, 73728);
    hipFuncSetAttribute((const void*)gemm2<EPI_GELU>,  hipFuncAttributeMaxDynamicSharedMemorySize, 73728);
    hipFuncSetAttribute((const void*)gemm2<EPI_PRIOR>, hipFuncAttributeMaxDynamicSharedMemorySize, 73728);
    attr_done = true;
  }

  dim3 blk(256);
  dim3 gblk(512);
  constexpr unsigned SH = 73728;   // ring-3 * 24KB -> 2 blocks/CU

  conv_w<<<dim3(1024, 6), blk, 0, stream>>>(Wq, Wk, Wv, Wp, We, Wc,
                                            Wqb, Wkb, Wvb, Wpb, Web, Wcb,
                                            1048576, 1048576, 1048576, 1048576, 4194304, 4194304);
  ew_pre<<<2048, blk, 0, stream>>>(x, pe, a1, w1, b1, a3, w3, b3, prior, xn, 2097152);

  // fused QKV: [8192,3072] = xn @ [Wq;Wk;Wv]^T
  gemm2<EPI_QKV><<<dim3(12, 64, 1), gblk, SH, stream>>>(xn, Wqb, Qb, 3072, 1024,
      0, 0, 8388608ll, nullptr, nullptr, nullptr, nullptr, nullptr, 0.f);
  transpose_k<<<dim3(16, 32, 4), blk, 0, stream>>>(Vb, Vt);

  // scores[b,t,s] = (Q·K)/32 - |t-s|
  gemm2<EPI_SCORES><<<dim3(8, 16, 4), gblk, SH, stream>>>(Qb, Kb, scores, 2048, 1024,
      2097152ll, 2097152ll, 4194304ll, nullptr, nullptr, nullptr, nullptr, nullptr, 0.03125f);
  softmax_k<<<8192, blk, 0, stream>>>(scores, probs);

  // out[b,t,d] = probs @ Vt
  gemm2<EPI_BF16><<<dim3(4, 16, 4), gblk, SH, stream>>>(probs, Vt, attno, 1024, 2048,
      4194304ll, 2097152ll, 2097152ll, nullptr, nullptr, nullptr, nullptr, nullptr, 0.f);

  // proj + dyt2
  gemm2<EPI_DYT><<<dim3(4, 64, 1), gblk, SH, stream>>>(attno, Wpb, h2, 1024, 1024,
      0, 0, 0, bp, a2, w2, b2, nullptr, 0.f);
  // expand + exact gelu
  gemm2<EPI_GELU><<<dim3(16, 64, 1), gblk, SH, stream>>>(h2, Web, eb, 4096, 1024,
      0, 0, 0, be, nullptr, nullptr, nullptr, nullptr, 0.f);
  // contract + bias + prior -> posterior
  gemm2<EPI_PRIOR><<<dim3(4, 64, 1), gblk, SH, stream>>>(eb, Wcb, out, 1024, 4096,
      0, 0, 0, bc, nullptr, nullptr, nullptr, prior, 0.f);

  loss_k<<<8192, blk, 0, stream>>>(prior, out, partial);
  loss_fin<<<1, 1024, 0, stream>>>(partial, out + 8388608);
}